// Round 7
// baseline (1017.061 us; speedup 1.0000x reference)
//
#include <hip/hip_runtime.h>
#include <hip/hip_bf16.h>

// Problem constants (B=2, S=2048, H=2048, NH=16, HD=128, FF=8192)
#define B_ 2
#define S_ 2048
#define H_ 2048
#define NH_ 16
#define HD_ 128
#define FF_ 8192

typedef __attribute__((ext_vector_type(8))) short bf16x8;  // 8 bf16 (4 VGPRs)
typedef __attribute__((ext_vector_type(4))) float f32x4;   // MFMA 16x16 accumulator

#define NEG_BIG (-1e30f)   // finite "minus infinity": avoids inf-inf NaN paths

// async global->LDS DMA, 16 B per lane; lds dest = wave-uniform base + lane*16
#define GLL16(gp, lp)                                                                    \
  __builtin_amdgcn_global_load_lds((const __attribute__((address_space(1))) void*)(gp),  \
                                   (__attribute__((address_space(3))) void*)(lp), 16, 0, 0)

__device__ __forceinline__ float b2f(unsigned short u) {
  union { unsigned int i; float f; } c; c.i = ((unsigned int)u) << 16; return c.f;
}
__device__ __forceinline__ unsigned short f2b(float f) {
  unsigned int u = __float_as_uint(f);
  u += 0x7fffu + ((u >> 16) & 1u);   // round-to-nearest-even
  return (unsigned short)(u >> 16);
}
// dtype-adaptive scalar load: f32 != 0 -> fp32 buffer, else bf16 buffer
__device__ __forceinline__ float ldf(const void* p, size_t i, int f32) {
  return f32 ? ((const float*)p)[i] : b2f(((const unsigned short*)p)[i]);
}
__device__ __forceinline__ void unpack8(uint4 r, float* f) {
  f[0] = b2f((unsigned short)(r.x & 0xffffu)); f[1] = b2f((unsigned short)(r.x >> 16));
  f[2] = b2f((unsigned short)(r.y & 0xffffu)); f[3] = b2f((unsigned short)(r.y >> 16));
  f[4] = b2f((unsigned short)(r.z & 0xffffu)); f[5] = b2f((unsigned short)(r.z >> 16));
  f[6] = b2f((unsigned short)(r.w & 0xffffu)); f[7] = b2f((unsigned short)(r.w >> 16));
}

// ---------------------------------------------------------------------------
// Input dtype detection (fp32 vs bf16)
// ---------------------------------------------------------------------------
__global__ void detect_k(const unsigned int* __restrict__ x, int* __restrict__ flagp) {
  if (threadIdx.x == 0) {
    int c = 0;
    for (int i = 0; i < 256; ++i) {
      unsigned int e = (x[i] >> 7) & 0xffu;  // bf16 exponent of low ushort
      c += (e >= 97u && e <= 130u) ? 1 : 0;
    }
    *flagp = (c < 128) ? 1 : 0;  // 1 = fp32 inputs, 0 = bf16 inputs
  }
}

// ---------------------------------------------------------------------------
// Transpose (input weights, dtype per flag) -> bf16: out[c][r] = in[r][c].
// ---------------------------------------------------------------------------
__global__ __launch_bounds__(256) void transpose_k(const void* __restrict__ in,
                                                   unsigned short* __restrict__ out,
                                                   int R, int C,
                                                   const int* __restrict__ flagp) {
  __shared__ unsigned short tile[32][33];
  int f32 = *flagp;
  int r0 = blockIdx.y * 32, c0 = blockIdx.x * 32;
  int tx = threadIdx.x & 31, ty = threadIdx.x >> 5;  // ty in [0,8)
#pragma unroll
  for (int p = 0; p < 4; ++p)
    tile[ty + p * 8][tx] = f2b(ldf(in, (size_t)(r0 + ty + p * 8) * C + c0 + tx, f32));
  __syncthreads();
#pragma unroll
  for (int p = 0; p < 4; ++p)
    out[(size_t)(c0 + ty + p * 8) * R + r0 + tx] = tile[tx][ty + p * 8];
}

// ---------------------------------------------------------------------------
// V transpose (bf16 ws -> bf16 ws): VT[b][h][d][s] = qkv[b*S+s][2H + h*HD + d]
// ---------------------------------------------------------------------------
__global__ __launch_bounds__(256) void v_transpose_k(const unsigned short* __restrict__ qkv,
                                                     unsigned short* __restrict__ VT) {
  __shared__ unsigned short tile[32][33];
  int bh = blockIdx.z;               // b*NH + h
  int b = bh >> 4, h = bh & 15;
  int s0 = blockIdx.x * 32, d0 = blockIdx.y * 32;
  int tx = threadIdx.x & 31, ty = threadIdx.x >> 5;
#pragma unroll
  for (int p = 0; p < 4; ++p) {
    int s = s0 + ty + p * 8;
    tile[ty + p * 8][tx] = qkv[(size_t)(b * S_ + s) * (3 * H_) + 2 * H_ + h * HD_ + d0 + tx];
  }
  __syncthreads();
#pragma unroll
  for (int p = 0; p < 4; ++p)
    VT[((size_t)bh * HD_ + d0 + ty + p * 8) * S_ + s0 + tx] = tile[tx][ty + p * 8];
}

// ---------------------------------------------------------------------------
// LayerNorm over rows of length H=2048.  One 256-thread block per row.
// ---------------------------------------------------------------------------
__global__ __launch_bounds__(256) void ln_k(const void* __restrict__ x,
                                            const void* __restrict__ g,
                                            const void* __restrict__ b,
                                            unsigned short* __restrict__ y,
                                            const int* __restrict__ flagp, int in_mode) {
  __shared__ float red[2][4];
  int f32 = *flagp;
  int xf = in_mode ? f32 : 0;
  int row = blockIdx.x;
  int t = threadIdx.x;
  float v[8];
  size_t base = (size_t)row * H_ + t * 8;
  if (xf) {
    const float4* p = reinterpret_cast<const float4*>((const float*)x + base);
    float4 u0 = p[0], u1 = p[1];
    v[0] = u0.x; v[1] = u0.y; v[2] = u0.z; v[3] = u0.w;
    v[4] = u1.x; v[5] = u1.y; v[6] = u1.z; v[7] = u1.w;
  } else {
    unpack8(*reinterpret_cast<const uint4*>((const unsigned short*)x + base), v);
  }
  float s1 = 0.f, s2 = 0.f;
#pragma unroll
  for (int i = 0; i < 8; ++i) { s1 += v[i]; s2 += v[i] * v[i]; }
#pragma unroll
  for (int off = 32; off > 0; off >>= 1) {
    s1 += __shfl_down(s1, off);
    s2 += __shfl_down(s2, off);
  }
  int w = t >> 6, lane = t & 63;
  if (lane == 0) { red[0][w] = s1; red[1][w] = s2; }
  __syncthreads();
  s1 = red[0][0] + red[0][1] + red[0][2] + red[0][3];
  s2 = red[1][0] + red[1][1] + red[1][2] + red[1][3];
  float mu = s1 * (1.0f / H_);
  float var = s2 * (1.0f / H_) - mu * mu;
  float rinv = rsqrtf(var + 1e-5f);
  float gv[8], bv[8];
#pragma unroll
  for (int i = 0; i < 8; ++i) {
    gv[i] = ldf(g, t * 8 + i, f32);
    bv[i] = ldf(b, t * 8 + i, f32);
  }
  unsigned int o[4];
#pragma unroll
  for (int i = 0; i < 4; ++i) {
    unsigned short lo = f2b((v[2 * i] - mu) * rinv * gv[2 * i] + bv[2 * i]);
    unsigned short hi = f2b((v[2 * i + 1] - mu) * rinv * gv[2 * i + 1] + bv[2 * i + 1]);
    o[i] = (unsigned int)lo | ((unsigned int)hi << 16);
  }
  uint4 ov; ov.x = o[0]; ov.y = o[1]; ov.z = o[2]; ov.w = o[3];
  *reinterpret_cast<uint4*>(y + base) = ov;
}

// ---------------------------------------------------------------------------
// 256x256 8-phase GEMM: C[M,N] = A[M,K] @ BT[N,K]^T (+gelu / fp32 partials).
// (unchanged from round 6 — best A/B config: single-barrier phase + supertile
// order + independent-first MF8.  FFN-up: 149.7 us, MfmaUtil 39.6, 0 confl.)
// ---------------------------------------------------------------------------
#define PH_BAR() do { asm volatile("" ::: "memory"); __builtin_amdgcn_s_barrier(); \
                      asm volatile("" ::: "memory"); } while (0)
#define VMC(n) asm volatile("s_waitcnt vmcnt(" #n ")" ::: "memory")

#define STA(buf_, h_, kt_) do {                                                        \
  GLL16(pA0 + (size_t)(h_) * 128 * K + (kt_) * 64, &LdsA[buf_][(h_) * 8192 + lw]);     \
  GLL16(pA1 + (size_t)(h_) * 128 * K + (kt_) * 64, &LdsA[buf_][(h_) * 8192 + 4096 + lw]); } while (0)
#define STB(buf_, h_, kt_) do {                                                        \
  GLL16(pB0 + (size_t)(h_) * 128 * K + (kt_) * 64, &LdsB[buf_][(h_) * 8192 + lw]);     \
  GLL16(pB1 + (size_t)(h_) * 128 * K + (kt_) * 64, &LdsB[buf_][(h_) * 8192 + 4096 + lw]); } while (0)

#define LDA4(AF, buf_, mb_) do { _Pragma("unroll")                                     \
  for (int mi_ = 0; mi_ < 4; ++mi_) {                                                  \
    const unsigned short* _p = &LdsA[buf_][(wr * 128 + ((mb_) + mi_) * 16 + l15) * 64];\
    AF[mi_][0] = *reinterpret_cast<const bf16x8*>(_p + cs0);                           \
    AF[mi_][1] = *reinterpret_cast<const bf16x8*>(_p + cs1); } } while (0)
#define LDB2(BF, buf_, nb_) do { _Pragma("unroll")                                     \
  for (int ni_ = 0; ni_ < 2; ++ni_) {                                                  \
    const unsigned short* _p = &LdsB[buf_][(wc * 64 + ((nb_) + ni_) * 16 + l15) * 64]; \
    BF[ni_][0] = *reinterpret_cast<const bf16x8*>(_p + cs0);                           \
    BF[ni_][1] = *reinterpret_cast<const bf16x8*>(_p + cs1); } } while (0)

// independent-first: all 8 K-half-0 MFMAs, then the 8 dependent K-half-1.
#define MF8(AF, BF, MO, NO) do { _Pragma("unroll")                                     \
  for (int h_ = 0; h_ < 2; ++h_) { _Pragma("unroll")                                   \
    for (int mi_ = 0; mi_ < 4; ++mi_) { _Pragma("unroll")                              \
      for (int ni_ = 0; ni_ < 2; ++ni_) {                                              \
        acc[(MO) + mi_][(NO) + ni_] = __builtin_amdgcn_mfma_f32_16x16x32_bf16(         \
            AF[mi_][h_], BF[ni_][h_], acc[(MO) + mi_][(NO) + ni_], 0, 0, 0);           \
      } } } } while (0)

#define PH_MFMA(AF, BF, MO, NO) do {                                                   \
  PH_BAR(); __builtin_amdgcn_s_setprio(1);                                             \
  MF8(AF, BF, MO, NO);                                                                 \
  __builtin_amdgcn_s_setprio(0); } while (0)

#define GITER(LAST, tO, tE2, tO2) do {                                                 \
  /* ph1 */                                                                            \
  LDA4(aL, 0, 0); LDB2(bL, 0, 0);                                                      \
  STA(1, 1, tO);                                                                       \
  PH_MFMA(aL, bL, 0, 0);                                                               \
  /* ph2 */                                                                            \
  LDB2(bH, 0, 2);                                                                      \
  PH_MFMA(aL, bH, 0, 2);                                                               \
  /* ph3 */                                                                            \
  LDA4(aH, 0, 4);                                                                      \
  if (!(LAST)) STB(0, 0, tE2);                                                         \
  PH_MFMA(aH, bL, 4, 0);                                                               \
  /* ph4 */                                                                            \
  if (!(LAST)) { STB(0, 1, tE2); STA(0, 0, tE2); VMC(6); } else { VMC(0); }            \
  PH_MFMA(aH, bH, 4, 2);                                                               \
  /* ph5 */                                                                            \
  LDA4(aL, 1, 0); LDB2(bL, 1, 0);                                                      \
  if (!(LAST)) STA(0, 1, tE2);                                                         \
  PH_MFMA(aL, bL, 0, 0);                                                               \
  /* ph6 */                                                                            \
  LDB2(bH, 1, 2);                                                                      \
  PH_MFMA(aL, bH, 0, 2);                                                               \
  /* ph7 */                                                                            \
  LDA4(aH, 1, 4);                                                                      \
  if (!(LAST)) STB(1, 0, tO2);                                                         \
  PH_MFMA(aH, bL, 4, 0);                                                               \
  /* ph8 */                                                                            \
  if (!(LAST)) { STB(1, 1, tO2); STA(1, 0, tO2); VMC(6); }                             \
  PH_MFMA(aH, bH, 4, 2);                                                               \
} while (0)

template <int EPI>
__global__ __launch_bounds__(512) void gemm256(const unsigned short* __restrict__ A,
                                               const unsigned short* __restrict__ BT,
                                               void* __restrict__ C,
                                               const void* __restrict__ resid,
                                               int M, int N, int K,
                                               const int* __restrict__ flagp,
                                               int resid_mode, int store_mode, int nbx,
                                               int nxy, int Klen,
                                               size_t pslice, int prow) {
  (void)M;
  __shared__ unsigned short LdsA[2][16384];   // [buf][256 rows x 64 cols]
  __shared__ unsigned short LdsB[2][16384];

  // XCD-contiguous remap (all call sites: gridDim.x % 8 == 0)
  unsigned nwg = gridDim.x, q = nwg >> 3;
  unsigned o = blockIdx.x;
  unsigned wg = (o & 7u) * q + (o >> 3);
  int ks = 0;
  if (nxy) { ks = (int)(wg / (unsigned)nxy); wg -= (unsigned)ks * (unsigned)nxy; }
  // 8-row supertile order (bijective: nby == 16 at every call site)
  int bx = (int)((wg >> 3) % (unsigned)nbx);
  int by = (int)((wg >> 3) / (unsigned)nbx) * 8 + (int)(wg & 7u);
  int m_base = by * 256, n_base = bx * 256;
  size_t koff = (size_t)ks * (size_t)Klen;

  int tid = threadIdx.x;
  int w = tid >> 6, lane = tid & 63;
  int l15 = lane & 15, quad = lane >> 4;
  int wr = w >> 2, wc = w & 3;                 // wave's (M-half, N-quarter)

  // staging geometry: per half-tile, wave w covers bytes [w*1024, w*1024+1024)
  // of each 8 KiB row-group; lane's local row / inverse-swizzled col-block:
  int row0 = w * 8 + (lane >> 3);              // 0..63
  int scb  = (lane & 7) ^ (lane >> 3);         // inverse swizzle of (row&7)
  const unsigned short* pA0 = A + (size_t)(m_base + row0) * K + koff + scb * 8;
  const unsigned short* pA1 = pA0 + (size_t)64 * K;
  const unsigned short* pB0 = BT + (size_t)(n_base + row0) * K + koff + scb * 8;
  const unsigned short* pB1 = pB0 + (size_t)64 * K;
  unsigned lw = (unsigned)w * 512;             // wave-uniform LDS elem base

  // frag-read addressing (read-side swizzle matches the staged layout)
  int cs0 = ((quad) ^ (l15 & 7)) * 8;          // K-half 0, 16B block
  int cs1 = ((4 + quad) ^ (l15 & 7)) * 8;      // K-half 1

  f32x4 acc[8][4];
#pragma unroll
  for (int i = 0; i < 8; ++i)
#pragma unroll
    for (int j = 0; j < 4; ++j) acc[i][j] = (f32x4){0.f, 0.f, 0.f, 0.f};

  bf16x8 aL[4][2], aH[4][2], bL[2][2], bH[2][2];

  // prologue: tile0 (buf0) complete + tile1 (buf1) minus A-hi; 14 loads out.
  STA(0, 0, 0); STA(0, 1, 0); STB(0, 0, 0); STB(0, 1, 0);
  STB(1, 0, 1); STB(1, 1, 1); STA(1, 0, 1);
  VMC(6);       // waits oldest 8 = all of tile0
  PH_BAR();

  int niter = Klen >> 7;                        // Klen / 128 (2 K-tiles per iter)
  for (int i = 0; i < niter - 1; ++i) GITER(0, 2 * i + 1, 2 * i + 2, 2 * i + 3);
  GITER(1, 2 * niter - 1, 0, 0);

  // epilogue.  C/D layout: col = lane&15, row = quad*4 + r  [verified m89/m91]
  int f32 = 0, rf = 0, sf = 0;
  if (EPI != 3) {
    f32 = *flagp;
    rf = resid_mode ? f32 : 0;
    sf = store_mode ? f32 : 0;
  }
#pragma unroll
  for (int mi = 0; mi < 8; ++mi) {
#pragma unroll
    for (int ni = 0; ni < 4; ++ni) {
#pragma unroll
      for (int r = 0; r < 4; ++r) {
        int row = m_base + wr * 128 + mi * 16 + quad * 4 + r;
        int col = n_base + wc * 64 + ni * 16 + l15;
        float v = acc[mi][ni][r];
        if (EPI == 3) {
          ((float*)C)[(size_t)ks * pslice + (size_t)row * prow + col] = v;
        } else {
          size_t idx = (size_t)row * N + col;
          if (EPI == 1) v += ldf(resid, idx, rf);
          if (EPI == 2) {
            float u = v;
            float tt = 0.7978845608028654f * (u + 0.044715f * u * u * u);
            tt = fminf(tt, 15.0f);                 // overflow guard
            float s = __expf(2.0f * tt);           // 0.5*(1+tanh(tt)) = s/(s+1)
            v = u * s / (s + 1.0f);
          }
          if (sf) ((float*)C)[idx] = v;
          else    ((unsigned short*)C)[idx] = f2b(v);
        }
      }
    }
  }
}

// ---------------------------------------------------------------------------
// Split-K reduction: out[r][c] = store(P0[r][c] + P1[r][c] + resid[r][c]).
// ---------------------------------------------------------------------------
__global__ __launch_bounds__(256) void red_k(const float* __restrict__ P,
                                             void* __restrict__ out,
                                             const void* __restrict__ resid,
                                             int prow, size_t pslice,
                                             const int* __restrict__ flagp,
                                             int resid_mode, int store_mode) {
  int f32 = *flagp;
  int rf = resid_mode ? f32 : 0;
  int sf = store_mode ? f32 : 0;
  size_t gid = (size_t)blockIdx.x * 256 + threadIdx.x;
  int r = (int)(gid >> 8);               // 2048 cols / 8 = 256 threads per row
  int c = ((int)gid & 255) * 8;
  size_t pb = (size_t)r * prow + c;
  const float4* p0 = reinterpret_cast<const float4*>(P + pb);
  const float4* p1 = reinterpret_cast<const float4*>(P + pslice + pb);
  float4 a0 = p0[0], a1 = p0[1];
  float4 b0 = p1[0], b1 = p1[1];
  float v[8] = {a0.x + b0.x, a0.y + b0.y, a0.z + b0.z, a0.w + b0.w,
                a1.x + b1.x, a1.y + b1.y, a1.z + b1.z, a1.w + b1.w};
  size_t ob = (size_t)r * 2048 + c;
  if (rf) {
    const float4* rp = reinterpret_cast<const float4*>((const float*)resid + ob);
    float4 r0 = rp[0], r1 = rp[1];
    v[0] += r0.x; v[1] += r0.y; v[2] += r0.z; v[3] += r0.w;
    v[4] += r1.x; v[5] += r1.y; v[6] += r1.z; v[7] += r1.w;
  } else {
    float rr[8];
    unpack8(*reinterpret_cast<const uint4*>((const unsigned short*)resid + ob), rr);
#pragma unroll
    for (int j = 0; j < 8; ++j) v[j] += rr[j];
  }
  if (sf) {
    float4 s0 = {v[0], v[1], v[2], v[3]}, s1 = {v[4], v[5], v[6], v[7]};
    float4* op = reinterpret_cast<float4*>((float*)out + ob);
    op[0] = s0; op[1] = s1;
  } else {
    unsigned int oo[4];
#pragma unroll
    for (int i = 0; i < 4; ++i)
      oo[i] = (unsigned int)f2b(v[2 * i]) | ((unsigned int)f2b(v[2 * i + 1]) << 16);
    uint4 ov; ov.x = oo[0]; ov.y = oo[1]; ov.z = oo[2]; ov.w = oo[3];
    *reinterpret_cast<uint4*>((unsigned short*)out + ob) = ov;
  }
}

// ---------------------------------------------------------------------------
// Causal flash attention, round-7: QBLK=128 (8 waves, 512 thr), KVBLK=64.
// One block per (128 q-rows, b*NH+h); wave w owns q rows [w*16, w*16+16).
// Staging amortized over 2x the MFMA work vs QBLK=64; KV HBM traffic halves;
// LDS = 32(K,2buf) + 32(V,2buf) + 16(Ps) = 80 KiB exactly -> 2 blocks/CU
// (16 waves/CU).  Ps pad removed: XOR col-swizzle cb^(row&7) at 16B blocks
// keeps b128 reads aligned (worst 8-way conflict on 2 reads/tile — negligible).
// Diagonal now spans two KV tiles; general wave-uniform mask predicate.
// Same 1-barrier double-buffered pipeline as round 4 (verified).
// Grid: 512 blocks (16 qb x 32 bh), bh-contiguous per XCD, qb reversed.
// ---------------------------------------------------------------------------
__global__ __launch_bounds__(512) void attn_k(const unsigned short* __restrict__ qkv,
                                              const unsigned short* __restrict__ VT,
                                              unsigned short* __restrict__ out) {
  __shared__ unsigned short Ks[2][64 * 128];  // [buf][kv][d], rows 256 B, swizzled
  __shared__ unsigned short Vs[2][128 * 64];  // [buf][d][kv], rows 128 B, swizzled
  __shared__ unsigned short Ps[8][16 * 64];   // per-wave P: [q][kv], XOR-swizzled
  unsigned o = blockIdx.x;                    // 0..511
  int xcd = (int)(o & 7u), j = (int)(o >> 3); // j in [0,64)
  int bh = xcd + 8 * (j >> 4);                // 4 heads per XCD
  int qb = 15 - (j & 15);                     // reversed: big blocks first
  int b = bh >> 4, h = bh & 15;
  int q0 = qb * 128;
  int tid = threadIdx.x;
  int w = tid >> 6, lane = tid & 63, l15 = lane & 15, quad = lane >> 4;
  const float scale = 0.08838834764831845f;  // 1/sqrt(128)

  // Q fragments in registers (read once; block-invariant)
  bf16x8 aq[4];
  {
    const unsigned short* qrow =
        qkv + (size_t)(b * S_ + q0 + w * 16 + l15) * (3 * H_) + h * HD_;
#pragma unroll
    for (int ks = 0; ks < 4; ++ks)
      aq[ks] = *reinterpret_cast<const bf16x8*>(qrow + ks * 32 + quad * 8);
  }

  f32x4 o_[8];
#pragma unroll
  for (int f = 0; f < 8; ++f) o_[f] = (f32x4){0.f, 0.f, 0.f, 0.f};
  float m_i[4], l_i[4];
#pragma unroll
  for (int r = 0; r < 4; ++r) { m_i[r] = NEG_BIG; l_i[r] = 0.f; }

  const unsigned short* kbase = qkv + (size_t)b * S_ * (3 * H_) + H_ + h * HD_;
  const unsigned short* vbase = VT + (size_t)bh * HD_ * S_;

  // 8-wave staging: wave w stages K rows [w*8,w*8+8) (2 GLL16) and V rows
  // [w*16,w*16+16) (2 GLL16).  Swizzle computed per t (row&7 depends on t).
#define ATTN_STAGE(buf_, kv0_) do {                                                     \
  _Pragma("unroll")                                                                     \
  for (int t = 0; t < 2; ++t) {                                                         \
    int krow = w * 8 + t * 4 + (lane >> 4);                                             \
    int ksz = (lane & 15) ^ (krow & 7);                                                 \
    GLL16(kbase + (size_t)((kv0_) + krow) * (3 * H_) + ksz * 8,                         \
          &Ks[buf_][(w * 8 + t * 4) * 128]);                                            \
    int vrow = w * 16 + t * 8 + (lane >> 3);                                            \
    int vsz = (lane & 7) ^ (vrow & 7);                                                  \
    GLL16(vbase + (size_t)vrow * S_ + (kv0_) + vsz * 8,                                 \
          &Vs[buf_][(w * 16 + t * 8) * 64]);                                            \
  } } while (0)

  // prologue: stage tile 0 into buf 0
  ATTN_STAGE(0, 0);
  __syncthreads();   // implicit vmcnt(0): tile 0 landed

  int nt = (q0 >> 6) + 2;   // KV tiles: kv up to q0+127
  int cur = 0;
  for (int it = 0; it < nt; ++it, cur ^= 1) {
    int kv0 = it * 64;
    // async-stage next tile into the other buffer (fenced by prev barrier)
    if (it + 1 < nt) ATTN_STAGE(cur ^ 1, kv0 + 64);

    // S = Q K^T  (wave's 16 q-rows x 64 kv-cols)
    f32x4 sc[4];
#pragma unroll
    for (int jj = 0; jj < 4; ++jj) sc[jj] = (f32x4){0.f, 0.f, 0.f, 0.f};
#pragma unroll
    for (int ks = 0; ks < 4; ++ks) {
#pragma unroll
      for (int jj = 0; jj < 4; ++jj) {
        int r = jj * 16 + l15;
        bf16x8 bk = *reinterpret_cast<const bf16x8*>(
            &Ks[cur][r * 128 + (((ks * 4 + quad) ^ (l15 & 7))) * 8]);
        sc[jj] = __builtin_amdgcn_mfma_f32_16x16x32_bf16(aq[ks], bk, sc[jj], 0, 0, 0);
      }
    }
    // causal mask: global kv = kv0 + jj*16+l15, global q = q0 + w*16 + quad*4+r
    int coff = kv0 - q0 - w * 16;            // wave-uniform
    bool needmask = (coff + 63 > 0);
#pragma unroll
    for (int jj = 0; jj < 4; ++jj)
#pragma unroll
      for (int r = 0; r < 4; ++r) {
        float s = sc[jj][r] * scale;
        if (needmask && (jj * 16 + l15 + coff > quad * 4 + r)) s = NEG_BIG;
        sc[jj][r] = s;
      }

    // online softmax (all finite arithmetic)
    float mx[4];
#pragma unroll
    for (int r = 0; r < 4; ++r) {
      mx[r] = sc[0][r];
#pragma unroll
      for (int jj = 1; jj < 4; ++jj) mx[r] = fmaxf(mx[r], sc[jj][r]);
    }
#pragma unroll
    for (int mm = 1; mm <= 8; mm <<= 1)
#pragma unroll
      for (int r = 0; r < 4; ++r) mx[r] = fmaxf(mx[r], __shfl_xor(mx[r], mm));
    float alpha[4];
#pragma unroll
    for (int r = 0; r < 4; ++r) {
      float mn = fmaxf(m_i[r], mx[r]);
      alpha[r] = __expf(m_i[r] - mn);
      m_i[r] = mn;
    }
    float pr[4][4], rs[4] = {0.f, 0.f, 0.f, 0.f};
#pragma unroll
    for (int jj = 0; jj < 4; ++jj)
#pragma unroll
      for (int r = 0; r < 4; ++r) {
        float p = __expf(sc[jj][r] - m_i[r]);
        pr[jj][r] = p;
        rs[r] += p;
      }
#pragma unroll
    for (int mm = 1; mm <= 8; mm <<= 1)
#pragma unroll
      for (int r = 0; r < 4; ++r) rs[r] += __shfl_xor(rs[r], mm);
#pragma unroll
    for (int r = 0; r < 4; ++r) l_i[r] = l_i[r] * alpha[r] + rs[r];
#pragma unroll
    for (int f = 0; f < 8; ++f)
#pragma unroll
      for (int r = 0; r < 4; ++r) o_[f][r] *= alpha[r];

    // P -> per-wave LDS, XOR-swizzled: row = quad*4+r, col = jj*16+l15,
    // phys = row*64 + ((cb ^ (row&7))*8 | (col&7)), cb = col>>3.
#pragma unroll
    for (int jj = 0; jj < 4; ++jj)
#pragma unroll
      for (int r = 0; r < 4; ++r) {
        int prow_ = quad * 4 + r;
        int cb = jj * 2 + (l15 >> 3);
        Ps[w][prow_ * 64 + ((cb ^ (prow_ & 7)) * 8) + (l15 & 7)] = f2b(pr[jj][r]);
      }

    // O += P @ V  (P as A-operand, V^T rows as B-operand)
#pragma unroll
    for (int ks2 = 0; ks2 < 2; ++ks2) {
      bf16x8 ap = *reinterpret_cast<const bf16x8*>(
          &Ps[w][l15 * 64 + (((ks2 * 4 + quad) ^ (l15 & 7))) * 8]);
#pragma unroll
      for (int f = 0; f < 8; ++f) {
        int r = f * 16 + l15;
        bf16x8 bv = *reinterpret_cast<const bf16x8*>(
            &Vs[cur][r * 64 + (((ks2 * 4 + quad) ^ (l15 & 7))) * 8]);
        o_[f] = __builtin_amdgcn_mfma_f32_16x16x32_bf16(ap, bv, o_[f], 0, 0, 0);
      }
    }

    // one barrier per tile: implicit vmcnt(0) waits this iter's stage loads
    // (issued ~a full tile of compute ago) + fences buf[cur] readers.
    __syncthreads();
  }

  float inv[4];
#pragma unroll
  for (int r = 0; r < 4; ++r) inv[r] = 1.0f / l_i[r];
#pragma unroll
  for (int f = 0; f < 8; ++f)
#pragma unroll
    for (int r = 0; r < 4; ++r)
      out[(size_t)(b * S_ + q0 + w * 16 + quad * 4 + r) * H_ + h * HD_ + f * 16 + l15] =
          f2b(o_[f][r] * inv[r]);
}

// ---------------------------------------------------------------------------
// Workspace plan (129 MB): see round-2 comments (unchanged).
// ---------------------------------------------------------------------------
extern "C" void kernel_launch(void* const* d_in, const int* in_sizes, int n_in,
                              void* d_out, int out_size, void* d_ws, size_t ws_size,
                              hipStream_t stream) {
  (void)in_sizes; (void)n_in; (void)out_size; (void)ws_size;
  const void* x     = d_in[0];
  // d_in[1] = mask: causal triu(k=1), reconstructed in-kernel -> unused
  const void* wq    = d_in[2];
  const void* wk    = d_in[3];
  const void* wv    = d_in[4];
  const void* wo    = d_in[5];
  const void* w_in  = d_in[6];
  const void* w_out = d_in[7];
  const void* g1    = d_in[8];
  const void* b1    = d_in[9];
  const void* g2    = d_in[10];
  const void* b2    = d_in[11];
  char* ws = (char*)d_ws;

  const size_t MB = 1024 * 1024;
  unsigned short* W  = (unsigned short*)(ws + 0 * MB);    // 32 MB region
  unsigned short* E  = (unsigned short*)(ws + 32 * MB);   // 16 MB region
  unsigned short* F  = (unsigned short*)(ws + 48 * MB);   // 64 MB region
  unsigned short* Hb = (unsigned short*)(ws + 112 * MB);  // 16 MB region
  int* flagp         = (int*)(ws + 128 * MB);

  unsigned short* wqkvT = W;                                // 24 MB
  unsigned short* xn    = E;
  unsigned short* qkv   = F;                                // 48 MB
  unsigned short* VT    = F + (size_t)B_ * S_ * 3 * H_;     // 16 MB (F tail)
  unsigned short* attnb = E;
  unsigned short* hbuf  = Hb;
  unsigned short* hn    = E;
  unsigned short* ff1   = F;                                // 64 MB
  float*          Pop   = (float*)F;                        // out-proj partials

  dim3 blk(256);
  dim3 gblk(512);
  // 0. detect input dtype (fp32 vs bf16)
  detect_k<<<1, 64, 0, stream>>>((const unsigned int*)x, flagp);
  // 1. transpose wq,wk,wv -> W (bf16)
  transpose_k<<<dim3(H_ / 32, H_ / 32), blk, 0, stream>>>(wq, wqkvT, H_, H_, flagp);
  transpose_k<<<dim3(H_ / 32, H_ / 32), blk, 0, stream>>>(wk, wqkvT + (size_t)H_ * H_, H_, H_, flagp);
  transpose_k<<<dim3(H_ / 32, H_ / 32), blk, 0, stream>>>(wv, wqkvT + (size_t)2 * H_ * H_, H_, H_, flagp);
  // 2. LN1: x (flag dtype) -> xn (bf16)
  ln_k<<<B_ * S_, blk, 0, stream>>>(x, g1, b1, xn, flagp, 1);
  // 3. fused QKV GEMM: (4096 x 2048) @ (2048 x 6144) -> qkv   [384 blocks]
  gemm256<0><<<dim3((3 * H_ / 256) * (B_ * S_ / 256)), gblk, 0, stream>>>(
      xn, wqkvT, qkv, nullptr, B_ * S_, 3 * H_, H_, flagp, 0, 0, 3 * H_ / 256,
      0, H_, 0, 0);
  // 4. V -> (B,NH,HD,S)
  v_transpose_k<<<dim3(S_ / 32, HD_ / 32, B_ * NH_), blk, 0, stream>>>(qkv, VT);
  // 5. causal flash attention -> attnb (E; xn dead)   [512 blocks, 512 thr]
  attn_k<<<dim3(S_ / 128 * B_ * NH_), dim3(512), 0, stream>>>(qkv, VT, attnb);
  // 6. transpose wo -> W (wqkvT dead after step 3)
  transpose_k<<<dim3(H_ / 32, H_ / 32), blk, 0, stream>>>(wo, W, H_, H_, flagp);
  // 7. out-proj, split-K=2 -> fp32 partials in F (qkv/VT dead)   [256 blocks]
  gemm256<3><<<dim3(2 * (H_ / 256) * (B_ * S_ / 256)), gblk, 0, stream>>>(
      attnb, W, (void*)Pop, nullptr, B_ * S_, H_, H_, flagp, 0, 0, H_ / 256,
      (H_ / 256) * (B_ * S_ / 256), H_ / 2, (size_t)B_ * S_ * H_, H_);
  // 7b. reduce + residual(x): hbuf = P0 + P1 + x  (bf16 store)
  red_k<<<dim3((B_ * S_ * H_) / (256 * 8)), blk, 0, stream>>>(
      Pop, hbuf, x, H_, (size_t)B_ * S_ * H_, flagp, 1, 0);
  // 8. LN2: hbuf (bf16) -> hn
  ln_k<<<B_ * S_, blk, 0, stream>>>(hbuf, g2, b2, hn, flagp, 0);
  // 9. transpose w_in -> W (woT dead)
  transpose_k<<<dim3(FF_ / 32, H_ / 32), blk, 0, stream>>>(w_in, W, H_, FF_, flagp);
  // 10. FFN up + GELU: -> ff1 (F; Pop dead)   [512 blocks]
  gemm256<2><<<dim3((FF_ / 256) * (B_ * S_ / 256)), gblk, 0, stream>>>(
      hn, W, ff1, nullptr, B_ * S_, FF_, H_, flagp, 0, 0, FF_ / 256,
      0, H_, 0, 0);
  // 11. transpose w_out -> W (winT dead)
  transpose_k<<<dim3(H_ / 32, FF_ / 32), blk, 0, stream>>>(w_out, W, FF_, H_, flagp);
  // 12. FFN down, split-K=2 -> fp32 partials overlaid in-place on ff1
  //     [256 blocks]  P_ks[r][c] = ((float*)ff1)[ks*2048 + r*4096 + c]
  gemm256<3><<<dim3(2 * (H_ / 256) * (B_ * S_ / 256)), gblk, 0, stream>>>(
      ff1, W, (void*)ff1, nullptr, B_ * S_, H_, FF_, flagp, 0, 0, H_ / 256,
      (H_ / 256) * (B_ * S_ / 256), FF_ / 2, (size_t)H_, 2 * H_);
  // 12b. reduce + residual(hbuf) -> d_out (flag dtype store)
  red_k<<<dim3((B_ * S_ * H_) / (256 * 8)), blk, 0, stream>>>(
      (const float*)ff1, d_out, hbuf, 2 * H_, (size_t)H_, flagp, 0, 1);
}

// Round 8
// 948.698 us; speedup vs baseline: 1.0721x; 1.0721x over previous
//
#include <hip/hip_runtime.h>
#include <hip/hip_bf16.h>

// Problem constants (B=2, S=2048, H=2048, NH=16, HD=128, FF=8192)
#define B_ 2
#define S_ 2048
#define H_ 2048
#define NH_ 16
#define HD_ 128
#define FF_ 8192

typedef __attribute__((ext_vector_type(8))) short bf16x8;  // 8 bf16 (4 VGPRs)
typedef __attribute__((ext_vector_type(4))) float f32x4;   // MFMA 16x16 accumulator

#define NEG_BIG (-1e30f)   // finite "minus infinity": avoids inf-inf NaN paths

// async global->LDS DMA, 16 B per lane; lds dest = wave-uniform base + lane*16
#define GLL16(gp, lp)                                                                    \
  __builtin_amdgcn_global_load_lds((const __attribute__((address_space(1))) void*)(gp),  \
                                   (__attribute__((address_space(3))) void*)(lp), 16, 0, 0)

__device__ __forceinline__ float b2f(unsigned short u) {
  union { unsigned int i; float f; } c; c.i = ((unsigned int)u) << 16; return c.f;
}
__device__ __forceinline__ unsigned short f2b(float f) {
  unsigned int u = __float_as_uint(f);
  u += 0x7fffu + ((u >> 16) & 1u);   // round-to-nearest-even
  return (unsigned short)(u >> 16);
}
// dtype-adaptive scalar load: f32 != 0 -> fp32 buffer, else bf16 buffer
__device__ __forceinline__ float ldf(const void* p, size_t i, int f32) {
  return f32 ? ((const float*)p)[i] : b2f(((const unsigned short*)p)[i]);
}
__device__ __forceinline__ void unpack8(uint4 r, float* f) {
  f[0] = b2f((unsigned short)(r.x & 0xffffu)); f[1] = b2f((unsigned short)(r.x >> 16));
  f[2] = b2f((unsigned short)(r.y & 0xffffu)); f[3] = b2f((unsigned short)(r.y >> 16));
  f[4] = b2f((unsigned short)(r.z & 0xffffu)); f[5] = b2f((unsigned short)(r.z >> 16));
  f[6] = b2f((unsigned short)(r.w & 0xffffu)); f[7] = b2f((unsigned short)(r.w >> 16));
}

// ---------------------------------------------------------------------------
// Input dtype detection (fp32 vs bf16)
// ---------------------------------------------------------------------------
__global__ void detect_k(const unsigned int* __restrict__ x, int* __restrict__ flagp) {
  if (threadIdx.x == 0) {
    int c = 0;
    for (int i = 0; i < 256; ++i) {
      unsigned int e = (x[i] >> 7) & 0xffu;  // bf16 exponent of low ushort
      c += (e >= 97u && e <= 130u) ? 1 : 0;
    }
    *flagp = (c < 128) ? 1 : 0;  // 1 = fp32 inputs, 0 = bf16 inputs
  }
}

// ---------------------------------------------------------------------------
// Transpose (input weights, dtype per flag) -> bf16: out[c][r] = in[r][c].
// ---------------------------------------------------------------------------
__global__ __launch_bounds__(256) void transpose_k(const void* __restrict__ in,
                                                   unsigned short* __restrict__ out,
                                                   int R, int C,
                                                   const int* __restrict__ flagp) {
  __shared__ unsigned short tile[32][33];
  int f32 = *flagp;
  int r0 = blockIdx.y * 32, c0 = blockIdx.x * 32;
  int tx = threadIdx.x & 31, ty = threadIdx.x >> 5;  // ty in [0,8)
#pragma unroll
  for (int p = 0; p < 4; ++p)
    tile[ty + p * 8][tx] = f2b(ldf(in, (size_t)(r0 + ty + p * 8) * C + c0 + tx, f32));
  __syncthreads();
#pragma unroll
  for (int p = 0; p < 4; ++p)
    out[(size_t)(c0 + ty + p * 8) * R + r0 + tx] = tile[tx][ty + p * 8];
}

// Fused wq/wk/wv transpose: blockIdx.z selects the source; -2 dispatches.
__global__ __launch_bounds__(256) void qkvw_transpose_k(const void* __restrict__ wq,
                                                        const void* __restrict__ wk,
                                                        const void* __restrict__ wv,
                                                        unsigned short* __restrict__ out,
                                                        const int* __restrict__ flagp) {
  __shared__ unsigned short tile[32][33];
  int f32 = *flagp;
  const void* in = (blockIdx.z == 0) ? wq : (blockIdx.z == 1) ? wk : wv;
  unsigned short* o = out + (size_t)blockIdx.z * H_ * H_;
  int r0 = blockIdx.y * 32, c0 = blockIdx.x * 32;
  int tx = threadIdx.x & 31, ty = threadIdx.x >> 5;
#pragma unroll
  for (int p = 0; p < 4; ++p)
    tile[ty + p * 8][tx] = f2b(ldf(in, (size_t)(r0 + ty + p * 8) * H_ + c0 + tx, f32));
  __syncthreads();
#pragma unroll
  for (int p = 0; p < 4; ++p)
    o[(size_t)(c0 + ty + p * 8) * H_ + r0 + tx] = tile[tx][ty + p * 8];
}

// ---------------------------------------------------------------------------
// V transpose (bf16 ws -> bf16 ws): VT[b][h][d][s] = qkv[b*S+s][2H + h*HD + d]
// ---------------------------------------------------------------------------
__global__ __launch_bounds__(256) void v_transpose_k(const unsigned short* __restrict__ qkv,
                                                     unsigned short* __restrict__ VT) {
  __shared__ unsigned short tile[32][33];
  int bh = blockIdx.z;               // b*NH + h
  int b = bh >> 4, h = bh & 15;
  int s0 = blockIdx.x * 32, d0 = blockIdx.y * 32;
  int tx = threadIdx.x & 31, ty = threadIdx.x >> 5;
#pragma unroll
  for (int p = 0; p < 4; ++p) {
    int s = s0 + ty + p * 8;
    tile[ty + p * 8][tx] = qkv[(size_t)(b * S_ + s) * (3 * H_) + 2 * H_ + h * HD_ + d0 + tx];
  }
  __syncthreads();
#pragma unroll
  for (int p = 0; p < 4; ++p)
    VT[((size_t)bh * HD_ + d0 + ty + p * 8) * S_ + s0 + tx] = tile[tx][ty + p * 8];
}

// ---------------------------------------------------------------------------
// LayerNorm over rows of length H=2048.  One 256-thread block per row.
// (used for LN1 only; LN2 is fused into red_ln_k)
// ---------------------------------------------------------------------------
__global__ __launch_bounds__(256) void ln_k(const void* __restrict__ x,
                                            const void* __restrict__ g,
                                            const void* __restrict__ b,
                                            unsigned short* __restrict__ y,
                                            const int* __restrict__ flagp, int in_mode) {
  __shared__ float red[2][4];
  int f32 = *flagp;
  int xf = in_mode ? f32 : 0;
  int row = blockIdx.x;
  int t = threadIdx.x;
  float v[8];
  size_t base = (size_t)row * H_ + t * 8;
  if (xf) {
    const float4* p = reinterpret_cast<const float4*>((const float*)x + base);
    float4 u0 = p[0], u1 = p[1];
    v[0] = u0.x; v[1] = u0.y; v[2] = u0.z; v[3] = u0.w;
    v[4] = u1.x; v[5] = u1.y; v[6] = u1.z; v[7] = u1.w;
  } else {
    unpack8(*reinterpret_cast<const uint4*>((const unsigned short*)x + base), v);
  }
  float s1 = 0.f, s2 = 0.f;
#pragma unroll
  for (int i = 0; i < 8; ++i) { s1 += v[i]; s2 += v[i] * v[i]; }
#pragma unroll
  for (int off = 32; off > 0; off >>= 1) {
    s1 += __shfl_down(s1, off);
    s2 += __shfl_down(s2, off);
  }
  int w = t >> 6, lane = t & 63;
  if (lane == 0) { red[0][w] = s1; red[1][w] = s2; }
  __syncthreads();
  s1 = red[0][0] + red[0][1] + red[0][2] + red[0][3];
  s2 = red[1][0] + red[1][1] + red[1][2] + red[1][3];
  float mu = s1 * (1.0f / H_);
  float var = s2 * (1.0f / H_) - mu * mu;
  float rinv = rsqrtf(var + 1e-5f);
  float gv[8], bv[8];
#pragma unroll
  for (int i = 0; i < 8; ++i) {
    gv[i] = ldf(g, t * 8 + i, f32);
    bv[i] = ldf(b, t * 8 + i, f32);
  }
  unsigned int o[4];
#pragma unroll
  for (int i = 0; i < 4; ++i) {
    unsigned short lo = f2b((v[2 * i] - mu) * rinv * gv[2 * i] + bv[2 * i]);
    unsigned short hi = f2b((v[2 * i + 1] - mu) * rinv * gv[2 * i + 1] + bv[2 * i + 1]);
    o[i] = (unsigned int)lo | ((unsigned int)hi << 16);
  }
  uint4 ov; ov.x = o[0]; ov.y = o[1]; ov.z = o[2]; ov.w = o[3];
  *reinterpret_cast<uint4*>(y + base) = ov;
}

// ---------------------------------------------------------------------------
// 256x256 8-phase GEMM: C[M,N] = A[M,K] @ BT[N,K]^T (+gelu / fp32 partials).
// (unchanged from round 6 — best A/B config: single-barrier phase + supertile
// order + independent-first MF8.  FFN-up @nominal clocks: 149.7 us, 39.6 Mfma.)
// ---------------------------------------------------------------------------
#define PH_BAR() do { asm volatile("" ::: "memory"); __builtin_amdgcn_s_barrier(); \
                      asm volatile("" ::: "memory"); } while (0)
#define VMC(n) asm volatile("s_waitcnt vmcnt(" #n ")" ::: "memory")

#define STA(buf_, h_, kt_) do {                                                        \
  GLL16(pA0 + (size_t)(h_) * 128 * K + (kt_) * 64, &LdsA[buf_][(h_) * 8192 + lw]);     \
  GLL16(pA1 + (size_t)(h_) * 128 * K + (kt_) * 64, &LdsA[buf_][(h_) * 8192 + 4096 + lw]); } while (0)
#define STB(buf_, h_, kt_) do {                                                        \
  GLL16(pB0 + (size_t)(h_) * 128 * K + (kt_) * 64, &LdsB[buf_][(h_) * 8192 + lw]);     \
  GLL16(pB1 + (size_t)(h_) * 128 * K + (kt_) * 64, &LdsB[buf_][(h_) * 8192 + 4096 + lw]); } while (0)

#define LDA4(AF, buf_, mb_) do { _Pragma("unroll")                                     \
  for (int mi_ = 0; mi_ < 4; ++mi_) {                                                  \
    const unsigned short* _p = &LdsA[buf_][(wr * 128 + ((mb_) + mi_) * 16 + l15) * 64];\
    AF[mi_][0] = *reinterpret_cast<const bf16x8*>(_p + cs0);                           \
    AF[mi_][1] = *reinterpret_cast<const bf16x8*>(_p + cs1); } } while (0)
#define LDB2(BF, buf_, nb_) do { _Pragma("unroll")                                     \
  for (int ni_ = 0; ni_ < 2; ++ni_) {                                                  \
    const unsigned short* _p = &LdsB[buf_][(wc * 64 + ((nb_) + ni_) * 16 + l15) * 64]; \
    BF[ni_][0] = *reinterpret_cast<const bf16x8*>(_p + cs0);                           \
    BF[ni_][1] = *reinterpret_cast<const bf16x8*>(_p + cs1); } } while (0)

// independent-first: all 8 K-half-0 MFMAs, then the 8 dependent K-half-1.
#define MF8(AF, BF, MO, NO) do { _Pragma("unroll")                                     \
  for (int h_ = 0; h_ < 2; ++h_) { _Pragma("unroll")                                   \
    for (int mi_ = 0; mi_ < 4; ++mi_) { _Pragma("unroll")                              \
      for (int ni_ = 0; ni_ < 2; ++ni_) {                                              \
        acc[(MO) + mi_][(NO) + ni_] = __builtin_amdgcn_mfma_f32_16x16x32_bf16(         \
            AF[mi_][h_], BF[ni_][h_], acc[(MO) + mi_][(NO) + ni_], 0, 0, 0);           \
      } } } } while (0)

#define PH_MFMA(AF, BF, MO, NO) do {                                                   \
  PH_BAR(); __builtin_amdgcn_s_setprio(1);                                             \
  MF8(AF, BF, MO, NO);                                                                 \
  __builtin_amdgcn_s_setprio(0); } while (0)

#define GITER(LAST, tO, tE2, tO2) do {                                                 \
  /* ph1 */                                                                            \
  LDA4(aL, 0, 0); LDB2(bL, 0, 0);                                                      \
  STA(1, 1, tO);                                                                       \
  PH_MFMA(aL, bL, 0, 0);                                                               \
  /* ph2 */                                                                            \
  LDB2(bH, 0, 2);                                                                      \
  PH_MFMA(aL, bH, 0, 2);                                                               \
  /* ph3 */                                                                            \
  LDA4(aH, 0, 4);                                                                      \
  if (!(LAST)) STB(0, 0, tE2);                                                         \
  PH_MFMA(aH, bL, 4, 0);                                                               \
  /* ph4 */                                                                            \
  if (!(LAST)) { STB(0, 1, tE2); STA(0, 0, tE2); VMC(6); } else { VMC(0); }            \
  PH_MFMA(aH, bH, 4, 2);                                                               \
  /* ph5 */                                                                            \
  LDA4(aL, 1, 0); LDB2(bL, 1, 0);                                                      \
  if (!(LAST)) STA(0, 1, tE2);                                                         \
  PH_MFMA(aL, bL, 0, 0);                                                               \
  /* ph6 */                                                                            \
  LDB2(bH, 1, 2);                                                                      \
  PH_MFMA(aL, bH, 0, 2);                                                               \
  /* ph7 */                                                                            \
  LDA4(aH, 1, 4);                                                                      \
  if (!(LAST)) STB(1, 0, tO2);                                                         \
  PH_MFMA(aH, bL, 4, 0);                                                               \
  /* ph8 */                                                                            \
  if (!(LAST)) { STB(1, 1, tO2); STA(1, 0, tO2); VMC(6); }                             \
  PH_MFMA(aH, bH, 4, 2);                                                               \
} while (0)

template <int EPI>
__global__ __launch_bounds__(512) void gemm256(const unsigned short* __restrict__ A,
                                               const unsigned short* __restrict__ BT,
                                               void* __restrict__ C,
                                               const void* __restrict__ resid,
                                               int M, int N, int K,
                                               const int* __restrict__ flagp,
                                               int resid_mode, int store_mode, int nbx,
                                               int nxy, int Klen,
                                               size_t pslice, int prow) {
  (void)M;
  __shared__ unsigned short LdsA[2][16384];   // [buf][256 rows x 64 cols]
  __shared__ unsigned short LdsB[2][16384];

  // XCD-contiguous remap (all call sites: gridDim.x % 8 == 0)
  unsigned nwg = gridDim.x, q = nwg >> 3;
  unsigned o = blockIdx.x;
  unsigned wg = (o & 7u) * q + (o >> 3);
  int ks = 0;
  if (nxy) { ks = (int)(wg / (unsigned)nxy); wg -= (unsigned)ks * (unsigned)nxy; }
  // 8-row supertile order (bijective: nby == 16 at every call site)
  int bx = (int)((wg >> 3) % (unsigned)nbx);
  int by = (int)((wg >> 3) / (unsigned)nbx) * 8 + (int)(wg & 7u);
  int m_base = by * 256, n_base = bx * 256;
  size_t koff = (size_t)ks * (size_t)Klen;

  int tid = threadIdx.x;
  int w = tid >> 6, lane = tid & 63;
  int l15 = lane & 15, quad = lane >> 4;
  int wr = w >> 2, wc = w & 3;                 // wave's (M-half, N-quarter)

  // staging geometry: per half-tile, wave w covers bytes [w*1024, w*1024+1024)
  // of each 8 KiB row-group; lane's local row / inverse-swizzled col-block:
  int row0 = w * 8 + (lane >> 3);              // 0..63
  int scb  = (lane & 7) ^ (lane >> 3);         // inverse swizzle of (row&7)
  const unsigned short* pA0 = A + (size_t)(m_base + row0) * K + koff + scb * 8;
  const unsigned short* pA1 = pA0 + (size_t)64 * K;
  const unsigned short* pB0 = BT + (size_t)(n_base + row0) * K + koff + scb * 8;
  const unsigned short* pB1 = pB0 + (size_t)64 * K;
  unsigned lw = (unsigned)w * 512;             // wave-uniform LDS elem base

  // frag-read addressing (read-side swizzle matches the staged layout)
  int cs0 = ((quad) ^ (l15 & 7)) * 8;          // K-half 0, 16B block
  int cs1 = ((4 + quad) ^ (l15 & 7)) * 8;      // K-half 1

  f32x4 acc[8][4];
#pragma unroll
  for (int i = 0; i < 8; ++i)
#pragma unroll
    for (int j = 0; j < 4; ++j) acc[i][j] = (f32x4){0.f, 0.f, 0.f, 0.f};

  bf16x8 aL[4][2], aH[4][2], bL[2][2], bH[2][2];

  // prologue: tile0 (buf0) complete + tile1 (buf1) minus A-hi; 14 loads out.
  STA(0, 0, 0); STA(0, 1, 0); STB(0, 0, 0); STB(0, 1, 0);
  STB(1, 0, 1); STB(1, 1, 1); STA(1, 0, 1);
  VMC(6);       // waits oldest 8 = all of tile0
  PH_BAR();

  int niter = Klen >> 7;                        // Klen / 128 (2 K-tiles per iter)
  for (int i = 0; i < niter - 1; ++i) GITER(0, 2 * i + 1, 2 * i + 2, 2 * i + 3);
  GITER(1, 2 * niter - 1, 0, 0);

  // epilogue.  C/D layout: col = lane&15, row = quad*4 + r  [verified m89/m91]
  int f32 = 0, rf = 0, sf = 0;
  if (EPI != 3) {
    f32 = *flagp;
    rf = resid_mode ? f32 : 0;
    sf = store_mode ? f32 : 0;
  }
#pragma unroll
  for (int mi = 0; mi < 8; ++mi) {
#pragma unroll
    for (int ni = 0; ni < 4; ++ni) {
#pragma unroll
      for (int r = 0; r < 4; ++r) {
        int row = m_base + wr * 128 + mi * 16 + quad * 4 + r;
        int col = n_base + wc * 64 + ni * 16 + l15;
        float v = acc[mi][ni][r];
        if (EPI == 3) {
          ((float*)C)[(size_t)ks * pslice + (size_t)row * prow + col] = v;
        } else {
          size_t idx = (size_t)row * N + col;
          if (EPI == 1) v += ldf(resid, idx, rf);
          if (EPI == 2) {
            float u = v;
            float tt = 0.7978845608028654f * (u + 0.044715f * u * u * u);
            tt = fminf(tt, 15.0f);                 // overflow guard
            float s = __expf(2.0f * tt);           // 0.5*(1+tanh(tt)) = s/(s+1)
            v = u * s / (s + 1.0f);
          }
          if (sf) ((float*)C)[idx] = v;
          else    ((unsigned short*)C)[idx] = f2b(v);
        }
      }
    }
  }
}

// ---------------------------------------------------------------------------
// Split-K reduction: out[r][c] = store(P0[r][c] + P1[r][c] + resid[r][c]).
// (used for FFN-down; out-proj uses the LN-fused variant below)
// ---------------------------------------------------------------------------
__global__ __launch_bounds__(256) void red_k(const float* __restrict__ P,
                                             void* __restrict__ out,
                                             const void* __restrict__ resid,
                                             int prow, size_t pslice,
                                             const int* __restrict__ flagp,
                                             int resid_mode, int store_mode) {
  int f32 = *flagp;
  int rf = resid_mode ? f32 : 0;
  int sf = store_mode ? f32 : 0;
  size_t gid = (size_t)blockIdx.x * 256 + threadIdx.x;
  int r = (int)(gid >> 8);               // 2048 cols / 8 = 256 threads per row
  int c = ((int)gid & 255) * 8;
  size_t pb = (size_t)r * prow + c;
  const float4* p0 = reinterpret_cast<const float4*>(P + pb);
  const float4* p1 = reinterpret_cast<const float4*>(P + pslice + pb);
  float4 a0 = p0[0], a1 = p0[1];
  float4 b0 = p1[0], b1 = p1[1];
  float v[8] = {a0.x + b0.x, a0.y + b0.y, a0.z + b0.z, a0.w + b0.w,
                a1.x + b1.x, a1.y + b1.y, a1.z + b1.z, a1.w + b1.w};
  size_t ob = (size_t)r * 2048 + c;
  if (rf) {
    const float4* rp = reinterpret_cast<const float4*>((const float*)resid + ob);
    float4 r0 = rp[0], r1 = rp[1];
    v[0] += r0.x; v[1] += r0.y; v[2] += r0.z; v[3] += r0.w;
    v[4] += r1.x; v[5] += r1.y; v[6] += r1.z; v[7] += r1.w;
  } else {
    float rr[8];
    unpack8(*reinterpret_cast<const uint4*>((const unsigned short*)resid + ob), rr);
#pragma unroll
    for (int j = 0; j < 8; ++j) v[j] += rr[j];
  }
  if (sf) {
    float4 s0 = {v[0], v[1], v[2], v[3]}, s1 = {v[4], v[5], v[6], v[7]};
    float4* op = reinterpret_cast<float4*>((float*)out + ob);
    op[0] = s0; op[1] = s1;
  } else {
    unsigned int oo[4];
#pragma unroll
    for (int i = 0; i < 4; ++i)
      oo[i] = (unsigned int)f2b(v[2 * i]) | ((unsigned int)f2b(v[2 * i + 1]) << 16);
    uint4 ov; ov.x = oo[0]; ov.y = oo[1]; ov.z = oo[2]; ov.w = oo[3];
    *reinterpret_cast<uint4*>((unsigned short*)out + ob) = ov;
  }
}

// ---------------------------------------------------------------------------
// Fused split-K reduce + residual + LayerNorm (out-proj path):
//   h = P0 + P1 + x;   hbuf = bf16(h);   hn = bf16(LN(h; g, b)).
// One 256-thread block per row (grid = B*S).  Saves one full 16MB-rw dispatch.
// ---------------------------------------------------------------------------
__global__ __launch_bounds__(256) void red_ln_k(const float* __restrict__ P,
                                                unsigned short* __restrict__ hbuf,
                                                unsigned short* __restrict__ hn,
                                                const void* __restrict__ resid,
                                                const void* __restrict__ g,
                                                const void* __restrict__ b,
                                                int prow, size_t pslice,
                                                const int* __restrict__ flagp) {
  __shared__ float red[2][4];
  int f32 = *flagp;
  int row = blockIdx.x;
  int t = threadIdx.x;
  int c = t * 8;
  size_t pb = (size_t)row * prow + c;
  const float4* p0 = reinterpret_cast<const float4*>(P + pb);
  const float4* p1 = reinterpret_cast<const float4*>(P + pslice + pb);
  float4 a0 = p0[0], a1 = p0[1];
  float4 b0 = p1[0], b1 = p1[1];
  float v[8] = {a0.x + b0.x, a0.y + b0.y, a0.z + b0.z, a0.w + b0.w,
                a1.x + b1.x, a1.y + b1.y, a1.z + b1.z, a1.w + b1.w};
  size_t ob = (size_t)row * H_ + c;
  if (f32) {
    const float4* rp = reinterpret_cast<const float4*>((const float*)resid + ob);
    float4 r0 = rp[0], r1 = rp[1];
    v[0] += r0.x; v[1] += r0.y; v[2] += r0.z; v[3] += r0.w;
    v[4] += r1.x; v[5] += r1.y; v[6] += r1.z; v[7] += r1.w;
  } else {
    float rr[8];
    unpack8(*reinterpret_cast<const uint4*>((const unsigned short*)resid + ob), rr);
#pragma unroll
    for (int j = 0; j < 8; ++j) v[j] += rr[j];
  }
  // write h (bf16)
  {
    unsigned int oo[4];
#pragma unroll
    for (int i = 0; i < 4; ++i)
      oo[i] = (unsigned int)f2b(v[2 * i]) | ((unsigned int)f2b(v[2 * i + 1]) << 16);
    uint4 ov; ov.x = oo[0]; ov.y = oo[1]; ov.z = oo[2]; ov.w = oo[3];
    *reinterpret_cast<uint4*>(hbuf + ob) = ov;
  }
  // LayerNorm over the row
  float s1 = 0.f, s2 = 0.f;
#pragma unroll
  for (int i = 0; i < 8; ++i) { s1 += v[i]; s2 += v[i] * v[i]; }
#pragma unroll
  for (int off = 32; off > 0; off >>= 1) {
    s1 += __shfl_down(s1, off);
    s2 += __shfl_down(s2, off);
  }
  int w = t >> 6, lane = t & 63;
  if (lane == 0) { red[0][w] = s1; red[1][w] = s2; }
  __syncthreads();
  s1 = red[0][0] + red[0][1] + red[0][2] + red[0][3];
  s2 = red[1][0] + red[1][1] + red[1][2] + red[1][3];
  float mu = s1 * (1.0f / H_);
  float var = s2 * (1.0f / H_) - mu * mu;
  float rinv = rsqrtf(var + 1e-5f);
  float gv[8], bv[8];
#pragma unroll
  for (int i = 0; i < 8; ++i) {
    gv[i] = ldf(g, c + i, f32);
    bv[i] = ldf(b, c + i, f32);
  }
  unsigned int o[4];
#pragma unroll
  for (int i = 0; i < 4; ++i) {
    unsigned short lo = f2b((v[2 * i] - mu) * rinv * gv[2 * i] + bv[2 * i]);
    unsigned short hi = f2b((v[2 * i + 1] - mu) * rinv * gv[2 * i + 1] + bv[2 * i + 1]);
    o[i] = (unsigned int)lo | ((unsigned int)hi << 16);
  }
  uint4 ov; ov.x = o[0]; ov.y = o[1]; ov.z = o[2]; ov.w = o[3];
  *reinterpret_cast<uint4*>(hn + ob) = ov;
}

// ---------------------------------------------------------------------------
// Causal flash attention, QBLK=128 (8 waves, 512 thr), KVBLK=64.
// (unchanged from round 7; passed with absmax 0.03125)
// ---------------------------------------------------------------------------
__global__ __launch_bounds__(512) void attn_k(const unsigned short* __restrict__ qkv,
                                              const unsigned short* __restrict__ VT,
                                              unsigned short* __restrict__ out) {
  __shared__ unsigned short Ks[2][64 * 128];  // [buf][kv][d], rows 256 B, swizzled
  __shared__ unsigned short Vs[2][128 * 64];  // [buf][d][kv], rows 128 B, swizzled
  __shared__ unsigned short Ps[8][16 * 64];   // per-wave P: [q][kv], XOR-swizzled
  unsigned o = blockIdx.x;                    // 0..511
  int xcd = (int)(o & 7u), j = (int)(o >> 3); // j in [0,64)
  int bh = xcd + 8 * (j >> 4);                // 4 heads per XCD
  int qb = 15 - (j & 15);                     // reversed: big blocks first
  int b = bh >> 4, h = bh & 15;
  int q0 = qb * 128;
  int tid = threadIdx.x;
  int w = tid >> 6, lane = tid & 63, l15 = lane & 15, quad = lane >> 4;
  const float scale = 0.08838834764831845f;  // 1/sqrt(128)

  // Q fragments in registers (read once; block-invariant)
  bf16x8 aq[4];
  {
    const unsigned short* qrow =
        qkv + (size_t)(b * S_ + q0 + w * 16 + l15) * (3 * H_) + h * HD_;
#pragma unroll
    for (int ks = 0; ks < 4; ++ks)
      aq[ks] = *reinterpret_cast<const bf16x8*>(qrow + ks * 32 + quad * 8);
  }

  f32x4 o_[8];
#pragma unroll
  for (int f = 0; f < 8; ++f) o_[f] = (f32x4){0.f, 0.f, 0.f, 0.f};
  float m_i[4], l_i[4];
#pragma unroll
  for (int r = 0; r < 4; ++r) { m_i[r] = NEG_BIG; l_i[r] = 0.f; }

  const unsigned short* kbase = qkv + (size_t)b * S_ * (3 * H_) + H_ + h * HD_;
  const unsigned short* vbase = VT + (size_t)bh * HD_ * S_;

  // 8-wave staging: wave w stages K rows [w*8,w*8+8) (2 GLL16) and V rows
  // [w*16,w*16+16) (2 GLL16).  Swizzle computed per t (row&7 depends on t).
#define ATTN_STAGE(buf_, kv0_) do {                                                     \
  _Pragma("unroll")                                                                     \
  for (int t = 0; t < 2; ++t) {                                                         \
    int krow = w * 8 + t * 4 + (lane >> 4);                                             \
    int ksz = (lane & 15) ^ (krow & 7);                                                 \
    GLL16(kbase + (size_t)((kv0_) + krow) * (3 * H_) + ksz * 8,                         \
          &Ks[buf_][(w * 8 + t * 4) * 128]);                                            \
    int vrow = w * 16 + t * 8 + (lane >> 3);                                            \
    int vsz = (lane & 7) ^ (vrow & 7);                                                  \
    GLL16(vbase + (size_t)vrow * S_ + (kv0_) + vsz * 8,                                 \
          &Vs[buf_][(w * 16 + t * 8) * 64]);                                            \
  } } while (0)

  // prologue: stage tile 0 into buf 0
  ATTN_STAGE(0, 0);
  __syncthreads();   // implicit vmcnt(0): tile 0 landed

  int nt = (q0 >> 6) + 2;   // KV tiles: kv up to q0+127
  int cur = 0;
  for (int it = 0; it < nt; ++it, cur ^= 1) {
    int kv0 = it * 64;
    // async-stage next tile into the other buffer (fenced by prev barrier)
    if (it + 1 < nt) ATTN_STAGE(cur ^ 1, kv0 + 64);

    // S = Q K^T  (wave's 16 q-rows x 64 kv-cols)
    f32x4 sc[4];
#pragma unroll
    for (int jj = 0; jj < 4; ++jj) sc[jj] = (f32x4){0.f, 0.f, 0.f, 0.f};
#pragma unroll
    for (int ks = 0; ks < 4; ++ks) {
#pragma unroll
      for (int jj = 0; jj < 4; ++jj) {
        int r = jj * 16 + l15;
        bf16x8 bk = *reinterpret_cast<const bf16x8*>(
            &Ks[cur][r * 128 + (((ks * 4 + quad) ^ (l15 & 7))) * 8]);
        sc[jj] = __builtin_amdgcn_mfma_f32_16x16x32_bf16(aq[ks], bk, sc[jj], 0, 0, 0);
      }
    }
    // causal mask: global kv = kv0 + jj*16+l15, global q = q0 + w*16 + quad*4+r
    int coff = kv0 - q0 - w * 16;            // wave-uniform
    bool needmask = (coff + 63 > 0);
#pragma unroll
    for (int jj = 0; jj < 4; ++jj)
#pragma unroll
      for (int r = 0; r < 4; ++r) {
        float s = sc[jj][r] * scale;
        if (needmask && (jj * 16 + l15 + coff > quad * 4 + r)) s = NEG_BIG;
        sc[jj][r] = s;
      }

    // online softmax (all finite arithmetic)
    float mx[4];
#pragma unroll
    for (int r = 0; r < 4; ++r) {
      mx[r] = sc[0][r];
#pragma unroll
      for (int jj = 1; jj < 4; ++jj) mx[r] = fmaxf(mx[r], sc[jj][r]);
    }
#pragma unroll
    for (int mm = 1; mm <= 8; mm <<= 1)
#pragma unroll
      for (int r = 0; r < 4; ++r) mx[r] = fmaxf(mx[r], __shfl_xor(mx[r], mm));
    float alpha[4];
#pragma unroll
    for (int r = 0; r < 4; ++r) {
      float mn = fmaxf(m_i[r], mx[r]);
      alpha[r] = __expf(m_i[r] - mn);
      m_i[r] = mn;
    }
    float pr[4][4], rs[4] = {0.f, 0.f, 0.f, 0.f};
#pragma unroll
    for (int jj = 0; jj < 4; ++jj)
#pragma unroll
      for (int r = 0; r < 4; ++r) {
        float p = __expf(sc[jj][r] - m_i[r]);
        pr[jj][r] = p;
        rs[r] += p;
      }
#pragma unroll
    for (int mm = 1; mm <= 8; mm <<= 1)
#pragma unroll
      for (int r = 0; r < 4; ++r) rs[r] += __shfl_xor(rs[r], mm);
#pragma unroll
    for (int r = 0; r < 4; ++r) l_i[r] = l_i[r] * alpha[r] + rs[r];
#pragma unroll
    for (int f = 0; f < 8; ++f)
#pragma unroll
      for (int r = 0; r < 4; ++r) o_[f][r] *= alpha[r];

    // P -> per-wave LDS, XOR-swizzled: row = quad*4+r, col = jj*16+l15,
    // phys = row*64 + ((cb ^ (row&7))*8 | (col&7)), cb = col>>3.
#pragma unroll
    for (int jj = 0; jj < 4; ++jj)
#pragma unroll
      for (int r = 0; r < 4; ++r) {
        int prow_ = quad * 4 + r;
        int cb = jj * 2 + (l15 >> 3);
        Ps[w][prow_ * 64 + ((cb ^ (prow_ & 7)) * 8) + (l15 & 7)] = f2b(pr[jj][r]);
      }

    // O += P @ V  (P as A-operand, V^T rows as B-operand)
#pragma unroll
    for (int ks2 = 0; ks2 < 2; ++ks2) {
      bf16x8 ap = *reinterpret_cast<const bf16x8*>(
          &Ps[w][l15 * 64 + (((ks2 * 4 + quad) ^ (l15 & 7))) * 8]);
#pragma unroll
      for (int f = 0; f < 8; ++f) {
        int r = f * 16 + l15;
        bf16x8 bv = *reinterpret_cast<const bf16x8*>(
            &Vs[cur][r * 64 + (((ks2 * 4 + quad) ^ (l15 & 7))) * 8]);
        o_[f] = __builtin_amdgcn_mfma_f32_16x16x32_bf16(ap, bv, o_[f], 0, 0, 0);
      }
    }

    // one barrier per tile: implicit vmcnt(0) waits this iter's stage loads
    // (issued ~a full tile of compute ago) + fences buf[cur] readers.
    __syncthreads();
  }

  float inv[4];
#pragma unroll
  for (int r = 0; r < 4; ++r) inv[r] = 1.0f / l_i[r];
#pragma unroll
  for (int f = 0; f < 8; ++f)
#pragma unroll
    for (int r = 0; r < 4; ++r)
      out[(size_t)(b * S_ + q0 + w * 16 + quad * 4 + r) * H_ + h * HD_ + f * 16 + l15] =
          f2b(o_[f][r] * inv[r]);
}

// ---------------------------------------------------------------------------
// Workspace plan (129 MB): see round-2 comments (unchanged).
// ---------------------------------------------------------------------------
extern "C" void kernel_launch(void* const* d_in, const int* in_sizes, int n_in,
                              void* d_out, int out_size, void* d_ws, size_t ws_size,
                              hipStream_t stream) {
  (void)in_sizes; (void)n_in; (void)out_size; (void)ws_size;
  const void* x     = d_in[0];
  // d_in[1] = mask: causal triu(k=1), reconstructed in-kernel -> unused
  const void* wq    = d_in[2];
  const void* wk    = d_in[3];
  const void* wv    = d_in[4];
  const void* wo    = d_in[5];
  const void* w_in  = d_in[6];
  const void* w_out = d_in[7];
  const void* g1    = d_in[8];
  const void* b1    = d_in[9];
  const void* g2    = d_in[10];
  const void* b2    = d_in[11];
  char* ws = (char*)d_ws;

  const size_t MB = 1024 * 1024;
  unsigned short* W  = (unsigned short*)(ws + 0 * MB);    // 32 MB region
  unsigned short* E  = (unsigned short*)(ws + 32 * MB);   // 16 MB region
  unsigned short* F  = (unsigned short*)(ws + 48 * MB);   // 64 MB region
  unsigned short* Hb = (unsigned short*)(ws + 112 * MB);  // 16 MB region
  int* flagp         = (int*)(ws + 128 * MB);

  unsigned short* wqkvT = W;                                // 24 MB
  unsigned short* xn    = E;
  unsigned short* qkv   = F;                                // 48 MB
  unsigned short* VT    = F + (size_t)B_ * S_ * 3 * H_;     // 16 MB (F tail)
  unsigned short* attnb = E;
  unsigned short* hbuf  = Hb;
  unsigned short* hn    = E;
  unsigned short* ff1   = F;                                // 64 MB
  float*          Pop   = (float*)F;                        // out-proj partials

  dim3 blk(256);
  dim3 gblk(512);
  // 0. detect input dtype (fp32 vs bf16)
  detect_k<<<1, 64, 0, stream>>>((const unsigned int*)x, flagp);
  // 1. transpose wq,wk,wv -> W (bf16), one fused dispatch
  qkvw_transpose_k<<<dim3(H_ / 32, H_ / 32, 3), blk, 0, stream>>>(wq, wk, wv, wqkvT, flagp);
  // 2. LN1: x (flag dtype) -> xn (bf16)
  ln_k<<<B_ * S_, blk, 0, stream>>>(x, g1, b1, xn, flagp, 1);
  // 3. fused QKV GEMM: (4096 x 2048) @ (2048 x 6144) -> qkv   [384 blocks]
  gemm256<0><<<dim3((3 * H_ / 256) * (B_ * S_ / 256)), gblk, 0, stream>>>(
      xn, wqkvT, qkv, nullptr, B_ * S_, 3 * H_, H_, flagp, 0, 0, 3 * H_ / 256,
      0, H_, 0, 0);
  // 4. V -> (B,NH,HD,S)
  v_transpose_k<<<dim3(S_ / 32, HD_ / 32, B_ * NH_), blk, 0, stream>>>(qkv, VT);
  // 5. causal flash attention -> attnb (E; xn dead)   [512 blocks, 512 thr]
  attn_k<<<dim3(S_ / 128 * B_ * NH_), dim3(512), 0, stream>>>(qkv, VT, attnb);
  // 6. transpose wo -> W (wqkvT dead after step 3)
  transpose_k<<<dim3(H_ / 32, H_ / 32), blk, 0, stream>>>(wo, W, H_, H_, flagp);
  // 7. out-proj, split-K=2 -> fp32 partials in F (qkv/VT dead)   [256 blocks]
  gemm256<3><<<dim3(2 * (H_ / 256) * (B_ * S_ / 256)), gblk, 0, stream>>>(
      attnb, W, (void*)Pop, nullptr, B_ * S_, H_, H_, flagp, 0, 0, H_ / 256,
      (H_ / 256) * (B_ * S_ / 256), H_ / 2, (size_t)B_ * S_ * H_, H_);
  // 7b. fused reduce + residual(x) + LN2: hbuf = P0+P1+x, hn = LN(hbuf)
  red_ln_k<<<dim3(B_ * S_), blk, 0, stream>>>(
      Pop, hbuf, hn, x, g2, b2, H_, (size_t)B_ * S_ * H_, flagp);
  // 8. transpose w_in -> W (woT dead)
  transpose_k<<<dim3(FF_ / 32, H_ / 32), blk, 0, stream>>>(w_in, W, H_, FF_, flagp);
  // 9. FFN up + GELU: -> ff1 (F; Pop dead)   [512 blocks]
  gemm256<2><<<dim3((FF_ / 256) * (B_ * S_ / 256)), gblk, 0, stream>>>(
      hn, W, ff1, nullptr, B_ * S_, FF_, H_, flagp, 0, 0, FF_ / 256,
      0, H_, 0, 0);
  // 10. transpose w_out -> W (winT dead)
  transpose_k<<<dim3(H_ / 32, FF_ / 32), blk, 0, stream>>>(w_out, W, FF_, H_, flagp);
  // 11. FFN down, split-K=2 -> fp32 partials overlaid in-place on ff1
  //     [256 blocks]  P_ks[r][c] = ((float*)ff1)[ks*2048 + r*4096 + c]
  gemm256<3><<<dim3(2 * (H_ / 256) * (B_ * S_ / 256)), gblk, 0, stream>>>(
      ff1, W, (void*)ff1, nullptr, B_ * S_, H_, FF_, flagp, 0, 0, H_ / 256,
      (H_ / 256) * (B_ * S_ / 256), FF_ / 2, (size_t)H_, 2 * H_);
  // 11b. reduce + residual(hbuf) -> d_out (flag dtype store)
  red_k<<<dim3((B_ * S_ * H_) / (256 * 8)), blk, 0, stream>>>(
      (const float*)ff1, d_out, hbuf, 2 * H_, (size_t)H_, flagp, 0, 1);
}

// Round 9
// 878.950 us; speedup vs baseline: 1.1571x; 1.0794x over previous
//
#include <hip/hip_runtime.h>
#include <hip/hip_bf16.h>

// Problem constants (B=2, S=2048, H=2048, NH=16, HD=128, FF=8192)
#define B_ 2
#define S_ 2048
#define H_ 2048
#define NH_ 16
#define HD_ 128
#define FF_ 8192

typedef __attribute__((ext_vector_type(8))) short bf16x8;  // 8 bf16 (4 VGPRs)
typedef __attribute__((ext_vector_type(4))) float f32x4;   // MFMA 16x16 accumulator

#define NEG_BIG (-1e30f)   // finite "minus infinity": avoids inf-inf NaN paths

// async global->LDS DMA, 16 B per lane; lds dest = wave-uniform base + lane*16
#define GLL16(gp, lp)                                                                    \
  __builtin_amdgcn_global_load_lds((const __attribute__((address_space(1))) void*)(gp),  \
                                   (__attribute__((address_space(3))) void*)(lp), 16, 0, 0)

__device__ __forceinline__ float b2f(unsigned short u) {
  union { unsigned int i; float f; } c; c.i = ((unsigned int)u) << 16; return c.f;
}
__device__ __forceinline__ unsigned short f2b(float f) {
  unsigned int u = __float_as_uint(f);
  u += 0x7fffu + ((u >> 16) & 1u);   // round-to-nearest-even
  return (unsigned short)(u >> 16);
}
// dtype-adaptive scalar load: f32 != 0 -> fp32 buffer, else bf16 buffer
__device__ __forceinline__ float ldf(const void* p, size_t i, int f32) {
  return f32 ? ((const float*)p)[i] : b2f(((const unsigned short*)p)[i]);
}
__device__ __forceinline__ void unpack8(uint4 r, float* f) {
  f[0] = b2f((unsigned short)(r.x & 0xffffu)); f[1] = b2f((unsigned short)(r.x >> 16));
  f[2] = b2f((unsigned short)(r.y & 0xffffu)); f[3] = b2f((unsigned short)(r.y >> 16));
  f[4] = b2f((unsigned short)(r.z & 0xffffu)); f[5] = b2f((unsigned short)(r.z >> 16));
  f[6] = b2f((unsigned short)(r.w & 0xffffu)); f[7] = b2f((unsigned short)(r.w >> 16));
}

// ---------------------------------------------------------------------------
// Input dtype detection (fp32 vs bf16)
// ---------------------------------------------------------------------------
__global__ void detect_k(const unsigned int* __restrict__ x, int* __restrict__ flagp) {
  if (threadIdx.x == 0) {
    int c = 0;
    for (int i = 0; i < 256; ++i) {
      unsigned int e = (x[i] >> 7) & 0xffu;  // bf16 exponent of low ushort
      c += (e >= 97u && e <= 130u) ? 1 : 0;
    }
    *flagp = (c < 128) ? 1 : 0;  // 1 = fp32 inputs, 0 = bf16 inputs
  }
}

// ---------------------------------------------------------------------------
// Transpose (input weights, dtype per flag) -> bf16: out[c][r] = in[r][c].
// ---------------------------------------------------------------------------
__global__ __launch_bounds__(256) void transpose_k(const void* __restrict__ in,
                                                   unsigned short* __restrict__ out,
                                                   int R, int C,
                                                   const int* __restrict__ flagp) {
  __shared__ unsigned short tile[32][33];
  int f32 = *flagp;
  int r0 = blockIdx.y * 32, c0 = blockIdx.x * 32;
  int tx = threadIdx.x & 31, ty = threadIdx.x >> 5;  // ty in [0,8)
#pragma unroll
  for (int p = 0; p < 4; ++p)
    tile[ty + p * 8][tx] = f2b(ldf(in, (size_t)(r0 + ty + p * 8) * C + c0 + tx, f32));
  __syncthreads();
#pragma unroll
  for (int p = 0; p < 4; ++p)
    out[(size_t)(c0 + ty + p * 8) * R + r0 + tx] = tile[tx][ty + p * 8];
}

// Fused wq/wk/wv transpose: blockIdx.z selects the source; -2 dispatches.
__global__ __launch_bounds__(256) void qkvw_transpose_k(const void* __restrict__ wq,
                                                        const void* __restrict__ wk,
                                                        const void* __restrict__ wv,
                                                        unsigned short* __restrict__ out,
                                                        const int* __restrict__ flagp) {
  __shared__ unsigned short tile[32][33];
  int f32 = *flagp;
  const void* in = (blockIdx.z == 0) ? wq : (blockIdx.z == 1) ? wk : wv;
  unsigned short* o = out + (size_t)blockIdx.z * H_ * H_;
  int r0 = blockIdx.y * 32, c0 = blockIdx.x * 32;
  int tx = threadIdx.x & 31, ty = threadIdx.x >> 5;
#pragma unroll
  for (int p = 0; p < 4; ++p)
    tile[ty + p * 8][tx] = f2b(ldf(in, (size_t)(r0 + ty + p * 8) * H_ + c0 + tx, f32));
  __syncthreads();
#pragma unroll
  for (int p = 0; p < 4; ++p)
    o[(size_t)(c0 + ty + p * 8) * H_ + r0 + tx] = tile[tx][ty + p * 8];
}

// ---------------------------------------------------------------------------
// V transpose (bf16 ws -> bf16 ws): VT[b][h][d][s] = qkv[b*S+s][2H + h*HD + d]
// ---------------------------------------------------------------------------
__global__ __launch_bounds__(256) void v_transpose_k(const unsigned short* __restrict__ qkv,
                                                     unsigned short* __restrict__ VT) {
  __shared__ unsigned short tile[32][33];
  int bh = blockIdx.z;               // b*NH + h
  int b = bh >> 4, h = bh & 15;
  int s0 = blockIdx.x * 32, d0 = blockIdx.y * 32;
  int tx = threadIdx.x & 31, ty = threadIdx.x >> 5;
#pragma unroll
  for (int p = 0; p < 4; ++p) {
    int s = s0 + ty + p * 8;
    tile[ty + p * 8][tx] = qkv[(size_t)(b * S_ + s) * (3 * H_) + 2 * H_ + h * HD_ + d0 + tx];
  }
  __syncthreads();
#pragma unroll
  for (int p = 0; p < 4; ++p)
    VT[((size_t)bh * HD_ + d0 + ty + p * 8) * S_ + s0 + tx] = tile[tx][ty + p * 8];
}

// ---------------------------------------------------------------------------
// LayerNorm over rows of length H=2048.  One 256-thread block per row.
// (used for LN1 only; LN2 is fused into red_ln_k)
// ---------------------------------------------------------------------------
__global__ __launch_bounds__(256) void ln_k(const void* __restrict__ x,
                                            const void* __restrict__ g,
                                            const void* __restrict__ b,
                                            unsigned short* __restrict__ y,
                                            const int* __restrict__ flagp, int in_mode) {
  __shared__ float red[2][4];
  int f32 = *flagp;
  int xf = in_mode ? f32 : 0;
  int row = blockIdx.x;
  int t = threadIdx.x;
  float v[8];
  size_t base = (size_t)row * H_ + t * 8;
  if (xf) {
    const float4* p = reinterpret_cast<const float4*>((const float*)x + base);
    float4 u0 = p[0], u1 = p[1];
    v[0] = u0.x; v[1] = u0.y; v[2] = u0.z; v[3] = u0.w;
    v[4] = u1.x; v[5] = u1.y; v[6] = u1.z; v[7] = u1.w;
  } else {
    unpack8(*reinterpret_cast<const uint4*>((const unsigned short*)x + base), v);
  }
  float s1 = 0.f, s2 = 0.f;
#pragma unroll
  for (int i = 0; i < 8; ++i) { s1 += v[i]; s2 += v[i] * v[i]; }
#pragma unroll
  for (int off = 32; off > 0; off >>= 1) {
    s1 += __shfl_down(s1, off);
    s2 += __shfl_down(s2, off);
  }
  int w = t >> 6, lane = t & 63;
  if (lane == 0) { red[0][w] = s1; red[1][w] = s2; }
  __syncthreads();
  s1 = red[0][0] + red[0][1] + red[0][2] + red[0][3];
  s2 = red[1][0] + red[1][1] + red[1][2] + red[1][3];
  float mu = s1 * (1.0f / H_);
  float var = s2 * (1.0f / H_) - mu * mu;
  float rinv = rsqrtf(var + 1e-5f);
  float gv[8], bv[8];
#pragma unroll
  for (int i = 0; i < 8; ++i) {
    gv[i] = ldf(g, t * 8 + i, f32);
    bv[i] = ldf(b, t * 8 + i, f32);
  }
  unsigned int o[4];
#pragma unroll
  for (int i = 0; i < 4; ++i) {
    unsigned short lo = f2b((v[2 * i] - mu) * rinv * gv[2 * i] + bv[2 * i]);
    unsigned short hi = f2b((v[2 * i + 1] - mu) * rinv * gv[2 * i + 1] + bv[2 * i + 1]);
    o[i] = (unsigned int)lo | ((unsigned int)hi << 16);
  }
  uint4 ov; ov.x = o[0]; ov.y = o[1]; ov.z = o[2]; ov.w = o[3];
  *reinterpret_cast<uint4*>(y + base) = ov;
}

// ---------------------------------------------------------------------------
// 256x256 8-phase GEMM: C[M,N] = A[M,K] @ BT[N,K]^T (+gelu / fp32 partials).
// (unchanged from round 6 — best A/B config: single-barrier phase + supertile
// order + independent-first MF8.  FFN-up @nominal clocks: 149.7 us, 39.6 Mfma.)
// ---------------------------------------------------------------------------
#define PH_BAR() do { asm volatile("" ::: "memory"); __builtin_amdgcn_s_barrier(); \
                      asm volatile("" ::: "memory"); } while (0)
#define VMC(n) asm volatile("s_waitcnt vmcnt(" #n ")" ::: "memory")

#define STA(buf_, h_, kt_) do {                                                        \
  GLL16(pA0 + (size_t)(h_) * 128 * K + (kt_) * 64, &LdsA[buf_][(h_) * 8192 + lw]);     \
  GLL16(pA1 + (size_t)(h_) * 128 * K + (kt_) * 64, &LdsA[buf_][(h_) * 8192 + 4096 + lw]); } while (0)
#define STB(buf_, h_, kt_) do {                                                        \
  GLL16(pB0 + (size_t)(h_) * 128 * K + (kt_) * 64, &LdsB[buf_][(h_) * 8192 + lw]);     \
  GLL16(pB1 + (size_t)(h_) * 128 * K + (kt_) * 64, &LdsB[buf_][(h_) * 8192 + 4096 + lw]); } while (0)

#define LDA4(AF, buf_, mb_) do { _Pragma("unroll")                                     \
  for (int mi_ = 0; mi_ < 4; ++mi_) {                                                  \
    const unsigned short* _p = &LdsA[buf_][(wr * 128 + ((mb_) + mi_) * 16 + l15) * 64];\
    AF[mi_][0] = *reinterpret_cast<const bf16x8*>(_p + cs0);                           \
    AF[mi_][1] = *reinterpret_cast<const bf16x8*>(_p + cs1); } } while (0)
#define LDB2(BF, buf_, nb_) do { _Pragma("unroll")                                     \
  for (int ni_ = 0; ni_ < 2; ++ni_) {                                                  \
    const unsigned short* _p = &LdsB[buf_][(wc * 64 + ((nb_) + ni_) * 16 + l15) * 64]; \
    BF[ni_][0] = *reinterpret_cast<const bf16x8*>(_p + cs0);                           \
    BF[ni_][1] = *reinterpret_cast<const bf16x8*>(_p + cs1); } } while (0)

// independent-first: all 8 K-half-0 MFMAs, then the 8 dependent K-half-1.
#define MF8(AF, BF, MO, NO) do { _Pragma("unroll")                                     \
  for (int h_ = 0; h_ < 2; ++h_) { _Pragma("unroll")                                   \
    for (int mi_ = 0; mi_ < 4; ++mi_) { _Pragma("unroll")                              \
      for (int ni_ = 0; ni_ < 2; ++ni_) {                                              \
        acc[(MO) + mi_][(NO) + ni_] = __builtin_amdgcn_mfma_f32_16x16x32_bf16(         \
            AF[mi_][h_], BF[ni_][h_], acc[(MO) + mi_][(NO) + ni_], 0, 0, 0);           \
      } } } } while (0)

#define PH_MFMA(AF, BF, MO, NO) do {                                                   \
  PH_BAR(); __builtin_amdgcn_s_setprio(1);                                             \
  MF8(AF, BF, MO, NO);                                                                 \
  __builtin_amdgcn_s_setprio(0); } while (0)

#define GITER(LAST, tO, tE2, tO2) do {                                                 \
  /* ph1 */                                                                            \
  LDA4(aL, 0, 0); LDB2(bL, 0, 0);                                                      \
  STA(1, 1, tO);                                                                       \
  PH_MFMA(aL, bL, 0, 0);                                                               \
  /* ph2 */                                                                            \
  LDB2(bH, 0, 2);                                                                      \
  PH_MFMA(aL, bH, 0, 2);                                                               \
  /* ph3 */                                                                            \
  LDA4(aH, 0, 4);                                                                      \
  if (!(LAST)) STB(0, 0, tE2);                                                         \
  PH_MFMA(aH, bL, 4, 0);                                                               \
  /* ph4 */                                                                            \
  if (!(LAST)) { STB(0, 1, tE2); STA(0, 0, tE2); VMC(6); } else { VMC(0); }            \
  PH_MFMA(aH, bH, 4, 2);                                                               \
  /* ph5 */                                                                            \
  LDA4(aL, 1, 0); LDB2(bL, 1, 0);                                                      \
  if (!(LAST)) STA(0, 1, tE2);                                                         \
  PH_MFMA(aL, bL, 0, 0);                                                               \
  /* ph6 */                                                                            \
  LDB2(bH, 1, 2);                                                                      \
  PH_MFMA(aL, bH, 0, 2);                                                               \
  /* ph7 */                                                                            \
  LDA4(aH, 1, 4);                                                                      \
  if (!(LAST)) STB(1, 0, tO2);                                                         \
  PH_MFMA(aH, bL, 4, 0);                                                               \
  /* ph8 */                                                                            \
  if (!(LAST)) { STB(1, 1, tO2); STA(1, 0, tO2); VMC(6); }                             \
  PH_MFMA(aH, bH, 4, 2);                                                               \
} while (0)

template <int EPI>
__global__ __launch_bounds__(512) void gemm256(const unsigned short* __restrict__ A,
                                               const unsigned short* __restrict__ BT,
                                               void* __restrict__ C,
                                               const void* __restrict__ resid,
                                               int M, int N, int K,
                                               const int* __restrict__ flagp,
                                               int resid_mode, int store_mode, int nbx,
                                               int nxy, int Klen,
                                               size_t pslice, int prow) {
  (void)M;
  __shared__ unsigned short LdsA[2][16384];   // [buf][256 rows x 64 cols]
  __shared__ unsigned short LdsB[2][16384];

  // XCD-contiguous remap (all call sites: gridDim.x % 8 == 0)
  unsigned nwg = gridDim.x, q = nwg >> 3;
  unsigned o = blockIdx.x;
  unsigned wg = (o & 7u) * q + (o >> 3);
  int ks = 0;
  if (nxy) { ks = (int)(wg / (unsigned)nxy); wg -= (unsigned)ks * (unsigned)nxy; }
  // 8-row supertile order (bijective: nby == 16 at every call site)
  int bx = (int)((wg >> 3) % (unsigned)nbx);
  int by = (int)((wg >> 3) / (unsigned)nbx) * 8 + (int)(wg & 7u);
  int m_base = by * 256, n_base = bx * 256;
  size_t koff = (size_t)ks * (size_t)Klen;

  int tid = threadIdx.x;
  int w = tid >> 6, lane = tid & 63;
  int l15 = lane & 15, quad = lane >> 4;
  int wr = w >> 2, wc = w & 3;                 // wave's (M-half, N-quarter)

  // staging geometry: per half-tile, wave w covers bytes [w*1024, w*1024+1024)
  // of each 8 KiB row-group; lane's local row / inverse-swizzled col-block:
  int row0 = w * 8 + (lane >> 3);              // 0..63
  int scb  = (lane & 7) ^ (lane >> 3);         // inverse swizzle of (row&7)
  const unsigned short* pA0 = A + (size_t)(m_base + row0) * K + koff + scb * 8;
  const unsigned short* pA1 = pA0 + (size_t)64 * K;
  const unsigned short* pB0 = BT + (size_t)(n_base + row0) * K + koff + scb * 8;
  const unsigned short* pB1 = pB0 + (size_t)64 * K;
  unsigned lw = (unsigned)w * 512;             // wave-uniform LDS elem base

  // frag-read addressing (read-side swizzle matches the staged layout)
  int cs0 = ((quad) ^ (l15 & 7)) * 8;          // K-half 0, 16B block
  int cs1 = ((4 + quad) ^ (l15 & 7)) * 8;      // K-half 1

  f32x4 acc[8][4];
#pragma unroll
  for (int i = 0; i < 8; ++i)
#pragma unroll
    for (int j = 0; j < 4; ++j) acc[i][j] = (f32x4){0.f, 0.f, 0.f, 0.f};

  bf16x8 aL[4][2], aH[4][2], bL[2][2], bH[2][2];

  // prologue: tile0 (buf0) complete + tile1 (buf1) minus A-hi; 14 loads out.
  STA(0, 0, 0); STA(0, 1, 0); STB(0, 0, 0); STB(0, 1, 0);
  STB(1, 0, 1); STB(1, 1, 1); STA(1, 0, 1);
  VMC(6);       // waits oldest 8 = all of tile0
  PH_BAR();

  int niter = Klen >> 7;                        // Klen / 128 (2 K-tiles per iter)
  for (int i = 0; i < niter - 1; ++i) GITER(0, 2 * i + 1, 2 * i + 2, 2 * i + 3);
  GITER(1, 2 * niter - 1, 0, 0);

  // epilogue.  C/D layout: col = lane&15, row = quad*4 + r  [verified m89/m91]
  int f32 = 0, rf = 0, sf = 0;
  if (EPI != 3) {
    f32 = *flagp;
    rf = resid_mode ? f32 : 0;
    sf = store_mode ? f32 : 0;
  }
#pragma unroll
  for (int mi = 0; mi < 8; ++mi) {
#pragma unroll
    for (int ni = 0; ni < 4; ++ni) {
#pragma unroll
      for (int r = 0; r < 4; ++r) {
        int row = m_base + wr * 128 + mi * 16 + quad * 4 + r;
        int col = n_base + wc * 64 + ni * 16 + l15;
        float v = acc[mi][ni][r];
        if (EPI == 3) {
          ((float*)C)[(size_t)ks * pslice + (size_t)row * prow + col] = v;
        } else {
          size_t idx = (size_t)row * N + col;
          if (EPI == 1) v += ldf(resid, idx, rf);
          if (EPI == 2) {
            float u = v;
            float tt = 0.7978845608028654f * (u + 0.044715f * u * u * u);
            tt = fminf(tt, 15.0f);                 // overflow guard
            float s = __expf(2.0f * tt);           // 0.5*(1+tanh(tt)) = s/(s+1)
            v = u * s / (s + 1.0f);
          }
          if (sf) ((float*)C)[idx] = v;
          else    ((unsigned short*)C)[idx] = f2b(v);
        }
      }
    }
  }
}

// ---------------------------------------------------------------------------
// Split-K reduction: out[r][c] = store(P0[r][c] + P1[r][c] + resid[r][c]).
// (used for FFN-down; out-proj uses the LN-fused variant below)
// ---------------------------------------------------------------------------
__global__ __launch_bounds__(256) void red_k(const float* __restrict__ P,
                                             void* __restrict__ out,
                                             const void* __restrict__ resid,
                                             int prow, size_t pslice,
                                             const int* __restrict__ flagp,
                                             int resid_mode, int store_mode) {
  int f32 = *flagp;
  int rf = resid_mode ? f32 : 0;
  int sf = store_mode ? f32 : 0;
  size_t gid = (size_t)blockIdx.x * 256 + threadIdx.x;
  int r = (int)(gid >> 8);               // 2048 cols / 8 = 256 threads per row
  int c = ((int)gid & 255) * 8;
  size_t pb = (size_t)r * prow + c;
  const float4* p0 = reinterpret_cast<const float4*>(P + pb);
  const float4* p1 = reinterpret_cast<const float4*>(P + pslice + pb);
  float4 a0 = p0[0], a1 = p0[1];
  float4 b0 = p1[0], b1 = p1[1];
  float v[8] = {a0.x + b0.x, a0.y + b0.y, a0.z + b0.z, a0.w + b0.w,
                a1.x + b1.x, a1.y + b1.y, a1.z + b1.z, a1.w + b1.w};
  size_t ob = (size_t)r * 2048 + c;
  if (rf) {
    const float4* rp = reinterpret_cast<const float4*>((const float*)resid + ob);
    float4 r0 = rp[0], r1 = rp[1];
    v[0] += r0.x; v[1] += r0.y; v[2] += r0.z; v[3] += r0.w;
    v[4] += r1.x; v[5] += r1.y; v[6] += r1.z; v[7] += r1.w;
  } else {
    float rr[8];
    unpack8(*reinterpret_cast<const uint4*>((const unsigned short*)resid + ob), rr);
#pragma unroll
    for (int j = 0; j < 8; ++j) v[j] += rr[j];
  }
  if (sf) {
    float4 s0 = {v[0], v[1], v[2], v[3]}, s1 = {v[4], v[5], v[6], v[7]};
    float4* op = reinterpret_cast<float4*>((float*)out + ob);
    op[0] = s0; op[1] = s1;
  } else {
    unsigned int oo[4];
#pragma unroll
    for (int i = 0; i < 4; ++i)
      oo[i] = (unsigned int)f2b(v[2 * i]) | ((unsigned int)f2b(v[2 * i + 1]) << 16);
    uint4 ov; ov.x = oo[0]; ov.y = oo[1]; ov.z = oo[2]; ov.w = oo[3];
    *reinterpret_cast<uint4*>((unsigned short*)out + ob) = ov;
  }
}

// ---------------------------------------------------------------------------
// Fused split-K reduce + residual + LayerNorm (out-proj path):
//   h = P0 + P1 + x;   hbuf = bf16(h);   hn = bf16(LN(h; g, b)).
// One 256-thread block per row (grid = B*S).  Saves one full 16MB-rw dispatch.
// ---------------------------------------------------------------------------
__global__ __launch_bounds__(256) void red_ln_k(const float* __restrict__ P,
                                                unsigned short* __restrict__ hbuf,
                                                unsigned short* __restrict__ hn,
                                                const void* __restrict__ resid,
                                                const void* __restrict__ g,
                                                const void* __restrict__ b,
                                                int prow, size_t pslice,
                                                const int* __restrict__ flagp) {
  __shared__ float red[2][4];
  int f32 = *flagp;
  int row = blockIdx.x;
  int t = threadIdx.x;
  int c = t * 8;
  size_t pb = (size_t)row * prow + c;
  const float4* p0 = reinterpret_cast<const float4*>(P + pb);
  const float4* p1 = reinterpret_cast<const float4*>(P + pslice + pb);
  float4 a0 = p0[0], a1 = p0[1];
  float4 b0 = p1[0], b1 = p1[1];
  float v[8] = {a0.x + b0.x, a0.y + b0.y, a0.z + b0.z, a0.w + b0.w,
                a1.x + b1.x, a1.y + b1.y, a1.z + b1.z, a1.w + b1.w};
  size_t ob = (size_t)row * H_ + c;
  if (f32) {
    const float4* rp = reinterpret_cast<const float4*>((const float*)resid + ob);
    float4 r0 = rp[0], r1 = rp[1];
    v[0] += r0.x; v[1] += r0.y; v[2] += r0.z; v[3] += r0.w;
    v[4] += r1.x; v[5] += r1.y; v[6] += r1.z; v[7] += r1.w;
  } else {
    float rr[8];
    unpack8(*reinterpret_cast<const uint4*>((const unsigned short*)resid + ob), rr);
#pragma unroll
    for (int j = 0; j < 8; ++j) v[j] += rr[j];
  }
  // write h (bf16)
  {
    unsigned int oo[4];
#pragma unroll
    for (int i = 0; i < 4; ++i)
      oo[i] = (unsigned int)f2b(v[2 * i]) | ((unsigned int)f2b(v[2 * i + 1]) << 16);
    uint4 ov; ov.x = oo[0]; ov.y = oo[1]; ov.z = oo[2]; ov.w = oo[3];
    *reinterpret_cast<uint4*>(hbuf + ob) = ov;
  }
  // LayerNorm over the row
  float s1 = 0.f, s2 = 0.f;
#pragma unroll
  for (int i = 0; i < 8; ++i) { s1 += v[i]; s2 += v[i] * v[i]; }
#pragma unroll
  for (int off = 32; off > 0; off >>= 1) {
    s1 += __shfl_down(s1, off);
    s2 += __shfl_down(s2, off);
  }
  int w = t >> 6, lane = t & 63;
  if (lane == 0) { red[0][w] = s1; red[1][w] = s2; }
  __syncthreads();
  s1 = red[0][0] + red[0][1] + red[0][2] + red[0][3];
  s2 = red[1][0] + red[1][1] + red[1][2] + red[1][3];
  float mu = s1 * (1.0f / H_);
  float var = s2 * (1.0f / H_) - mu * mu;
  float rinv = rsqrtf(var + 1e-5f);
  float gv[8], bv[8];
#pragma unroll
  for (int i = 0; i < 8; ++i) {
    gv[i] = ldf(g, c + i, f32);
    bv[i] = ldf(b, c + i, f32);
  }
  unsigned int o[4];
#pragma unroll
  for (int i = 0; i < 4; ++i) {
    unsigned short lo = f2b((v[2 * i] - mu) * rinv * gv[2 * i] + bv[2 * i]);
    unsigned short hi = f2b((v[2 * i + 1] - mu) * rinv * gv[2 * i + 1] + bv[2 * i + 1]);
    o[i] = (unsigned int)lo | ((unsigned int)hi << 16);
  }
  uint4 ov; ov.x = o[0]; ov.y = o[1]; ov.z = o[2]; ov.w = o[3];
  *reinterpret_cast<uint4*>(hn + ob) = ov;
}

// ---------------------------------------------------------------------------
// Causal flash attention, round-9: QBLK=128 (8 waves), PAIRED for balance.
// Round-8 diagnosis: 512 blocks at 2/CU capacity co-located the two LONGEST
// blocks (o and o+256 have equal qb) on the same CUs -> runtime = 2 stacked
// worst-case blocks, avg occupancy 14%.  Fix: each block processes the q-tile
// PAIR (15-p, p) -> every block = exactly 34 KV-tiles; grid 256 = 1 block/CU.
// Also: defer-max (T13, THR=8) — skip O/l rescale and m-update when
// __all(max growth <= 8); wave-uniform branch; first tile takes normal path.
// Per-tile pipeline unchanged (double-buffered K/V, 1 barrier/tile).
// ---------------------------------------------------------------------------
__global__ __launch_bounds__(512) void attn_k(const unsigned short* __restrict__ qkv,
                                              const unsigned short* __restrict__ VT,
                                              unsigned short* __restrict__ out) {
  __shared__ unsigned short Ks[2][64 * 128];  // [buf][kv][d], rows 256 B, swizzled
  __shared__ unsigned short Vs[2][128 * 64];  // [buf][d][kv], rows 128 B, swizzled
  __shared__ unsigned short Ps[8][16 * 64];   // per-wave P: [q][kv], XOR-swizzled
  unsigned o = blockIdx.x;                    // 0..255
  int xcd = (int)(o & 7u), j = (int)(o >> 3); // j in [0,32)
  int bh = xcd + 8 * (j & 3);                 // 4 heads per XCD
  int pair = j >> 2;                          // 0..7
  int b = bh >> 4, h = bh & 15;
  int tid = threadIdx.x;
  int w = tid >> 6, lane = tid & 63, l15 = lane & 15, quad = lane >> 4;
  const float scale = 0.08838834764831845f;  // 1/sqrt(128)

  const unsigned short* kbase = qkv + (size_t)b * S_ * (3 * H_) + H_ + h * HD_;
  const unsigned short* vbase = VT + (size_t)bh * HD_ * S_;

#define ATTN_STAGE(buf_, kv0_) do {                                                     \
  _Pragma("unroll")                                                                     \
  for (int t = 0; t < 2; ++t) {                                                         \
    int krow = w * 8 + t * 4 + (lane >> 4);                                             \
    int ksz = (lane & 15) ^ (krow & 7);                                                 \
    GLL16(kbase + (size_t)((kv0_) + krow) * (3 * H_) + ksz * 8,                         \
          &Ks[buf_][(w * 8 + t * 4) * 128]);                                            \
    int vrow = w * 16 + t * 8 + (lane >> 3);                                            \
    int vsz = (lane & 7) ^ (vrow & 7);                                                  \
    GLL16(vbase + (size_t)vrow * S_ + (kv0_) + vsz * 8,                                 \
          &Vs[buf_][(w * 16 + t * 8) * 64]);                                            \
  } } while (0)

#pragma unroll 1
  for (int half = 0; half < 2; ++half) {
    int qb = half ? pair : (15 - pair);       // big q-tile first
    int q0 = qb * 128;

    // Q fragments in registers (block-invariant within this half)
    bf16x8 aq[4];
    {
      const unsigned short* qrow =
          qkv + (size_t)(b * S_ + q0 + w * 16 + l15) * (3 * H_) + h * HD_;
#pragma unroll
      for (int ks = 0; ks < 4; ++ks)
        aq[ks] = *reinterpret_cast<const bf16x8*>(qrow + ks * 32 + quad * 8);
    }

    f32x4 o_[8];
#pragma unroll
    for (int f = 0; f < 8; ++f) o_[f] = (f32x4){0.f, 0.f, 0.f, 0.f};
    float m_i[4], l_i[4];
#pragma unroll
    for (int r = 0; r < 4; ++r) { m_i[r] = NEG_BIG; l_i[r] = 0.f; }

    // prologue: stage tile 0 into buf 0 (prev half's readers fenced by its
    // final barrier; the following barrier waits these loads)
    ATTN_STAGE(0, 0);
    __syncthreads();

    int nt = (q0 >> 6) + 2;   // KV tiles: kv up to q0+127
    int cur = 0;
    for (int it = 0; it < nt; ++it, cur ^= 1) {
      int kv0 = it * 64;
      if (it + 1 < nt) ATTN_STAGE(cur ^ 1, kv0 + 64);

      // S = Q K^T  (wave's 16 q-rows x 64 kv-cols)
      f32x4 sc[4];
#pragma unroll
      for (int jj = 0; jj < 4; ++jj) sc[jj] = (f32x4){0.f, 0.f, 0.f, 0.f};
#pragma unroll
      for (int ks = 0; ks < 4; ++ks) {
#pragma unroll
        for (int jj = 0; jj < 4; ++jj) {
          int r = jj * 16 + l15;
          bf16x8 bk = *reinterpret_cast<const bf16x8*>(
              &Ks[cur][r * 128 + (((ks * 4 + quad) ^ (l15 & 7))) * 8]);
          sc[jj] = __builtin_amdgcn_mfma_f32_16x16x32_bf16(aq[ks], bk, sc[jj], 0, 0, 0);
        }
      }
      // causal mask: kv = kv0 + jj*16+l15 vs q = q0 + w*16 + quad*4+r
      int coff = kv0 - q0 - w * 16;            // wave-uniform
      bool needmask = (coff + 63 > 0);
#pragma unroll
      for (int jj = 0; jj < 4; ++jj)
#pragma unroll
        for (int r = 0; r < 4; ++r) {
          float s = sc[jj][r] * scale;
          if (needmask && (jj * 16 + l15 + coff > quad * 4 + r)) s = NEG_BIG;
          sc[jj][r] = s;
        }

      // online softmax with defer-max (THR=8)
      float mx[4];
#pragma unroll
      for (int r = 0; r < 4; ++r) {
        mx[r] = sc[0][r];
#pragma unroll
        for (int jj = 1; jj < 4; ++jj) mx[r] = fmaxf(mx[r], sc[jj][r]);
      }
#pragma unroll
      for (int mm = 1; mm <= 8; mm <<= 1)
#pragma unroll
        for (int r = 0; r < 4; ++r) mx[r] = fmaxf(mx[r], __shfl_xor(mx[r], mm));
      float d0 = fmaxf(fmaxf(mx[0] - m_i[0], mx[1] - m_i[1]),
                       fmaxf(mx[2] - m_i[2], mx[3] - m_i[3]));
      if (!__all(d0 <= 8.0f)) {
#pragma unroll
        for (int r = 0; r < 4; ++r) {
          float mn = fmaxf(m_i[r], mx[r]);
          float alpha = __expf(m_i[r] - mn);
          m_i[r] = mn;
          l_i[r] *= alpha;
#pragma unroll
          for (int f = 0; f < 8; ++f) o_[f][r] *= alpha;
        }
      }
      float pr[4][4], rs[4] = {0.f, 0.f, 0.f, 0.f};
#pragma unroll
      for (int jj = 0; jj < 4; ++jj)
#pragma unroll
        for (int r = 0; r < 4; ++r) {
          float p = __expf(sc[jj][r] - m_i[r]);
          pr[jj][r] = p;
          rs[r] += p;
        }
#pragma unroll
      for (int mm = 1; mm <= 8; mm <<= 1)
#pragma unroll
        for (int r = 0; r < 4; ++r) rs[r] += __shfl_xor(rs[r], mm);
#pragma unroll
      for (int r = 0; r < 4; ++r) l_i[r] += rs[r];

      // P -> per-wave LDS, XOR-swizzled
#pragma unroll
      for (int jj = 0; jj < 4; ++jj)
#pragma unroll
        for (int r = 0; r < 4; ++r) {
          int prow_ = quad * 4 + r;
          int cb = jj * 2 + (l15 >> 3);
          Ps[w][prow_ * 64 + ((cb ^ (prow_ & 7)) * 8) + (l15 & 7)] = f2b(pr[jj][r]);
        }

      // O += P @ V
#pragma unroll
      for (int ks2 = 0; ks2 < 2; ++ks2) {
        bf16x8 ap = *reinterpret_cast<const bf16x8*>(
            &Ps[w][l15 * 64 + (((ks2 * 4 + quad) ^ (l15 & 7))) * 8]);
#pragma unroll
        for (int f = 0; f < 8; ++f) {
          int r = f * 16 + l15;
          bf16x8 bv = *reinterpret_cast<const bf16x8*>(
              &Vs[cur][r * 64 + (((ks2 * 4 + quad) ^ (l15 & 7))) * 8]);
          o_[f] = __builtin_amdgcn_mfma_f32_16x16x32_bf16(ap, bv, o_[f], 0, 0, 0);
        }
      }

      // one barrier per tile: implicit vmcnt(0) waits this iter's stage loads
      // (issued a full tile of compute ago) + fences buf[cur] readers.
      __syncthreads();
    }

    float inv[4];
#pragma unroll
    for (int r = 0; r < 4; ++r) inv[r] = 1.0f / l_i[r];
#pragma unroll
    for (int f = 0; f < 8; ++f)
#pragma unroll
      for (int r = 0; r < 4; ++r)
        out[(size_t)(b * S_ + q0 + w * 16 + quad * 4 + r) * H_ + h * HD_ + f * 16 + l15] =
            f2b(o_[f][r] * inv[r]);
  }
}

// ---------------------------------------------------------------------------
// Workspace plan (129 MB): see round-2 comments (unchanged).
// ---------------------------------------------------------------------------
extern "C" void kernel_launch(void* const* d_in, const int* in_sizes, int n_in,
                              void* d_out, int out_size, void* d_ws, size_t ws_size,
                              hipStream_t stream) {
  (void)in_sizes; (void)n_in; (void)out_size; (void)ws_size;
  const void* x     = d_in[0];
  // d_in[1] = mask: causal triu(k=1), reconstructed in-kernel -> unused
  const void* wq    = d_in[2];
  const void* wk    = d_in[3];
  const void* wv    = d_in[4];
  const void* wo    = d_in[5];
  const void* w_in  = d_in[6];
  const void* w_out = d_in[7];
  const void* g1    = d_in[8];
  const void* b1    = d_in[9];
  const void* g2    = d_in[10];
  const void* b2    = d_in[11];
  char* ws = (char*)d_ws;

  const size_t MB = 1024 * 1024;
  unsigned short* W  = (unsigned short*)(ws + 0 * MB);    // 32 MB region
  unsigned short* E  = (unsigned short*)(ws + 32 * MB);   // 16 MB region
  unsigned short* F  = (unsigned short*)(ws + 48 * MB);   // 64 MB region
  unsigned short* Hb = (unsigned short*)(ws + 112 * MB);  // 16 MB region
  int* flagp         = (int*)(ws + 128 * MB);

  unsigned short* wqkvT = W;                                // 24 MB
  unsigned short* xn    = E;
  unsigned short* qkv   = F;                                // 48 MB
  unsigned short* VT    = F + (size_t)B_ * S_ * 3 * H_;     // 16 MB (F tail)
  unsigned short* attnb = E;
  unsigned short* hbuf  = Hb;
  unsigned short* hn    = E;
  unsigned short* ff1   = F;                                // 64 MB
  float*          Pop   = (float*)F;                        // out-proj partials

  dim3 blk(256);
  dim3 gblk(512);
  // 0. detect input dtype (fp32 vs bf16)
  detect_k<<<1, 64, 0, stream>>>((const unsigned int*)x, flagp);
  // 1. transpose wq,wk,wv -> W (bf16), one fused dispatch
  qkvw_transpose_k<<<dim3(H_ / 32, H_ / 32, 3), blk, 0, stream>>>(wq, wk, wv, wqkvT, flagp);
  // 2. LN1: x (flag dtype) -> xn (bf16)
  ln_k<<<B_ * S_, blk, 0, stream>>>(x, g1, b1, xn, flagp, 1);
  // 3. fused QKV GEMM: (4096 x 2048) @ (2048 x 6144) -> qkv   [384 blocks]
  gemm256<0><<<dim3((3 * H_ / 256) * (B_ * S_ / 256)), gblk, 0, stream>>>(
      xn, wqkvT, qkv, nullptr, B_ * S_, 3 * H_, H_, flagp, 0, 0, 3 * H_ / 256,
      0, H_, 0, 0);
  // 4. V -> (B,NH,HD,S)
  v_transpose_k<<<dim3(S_ / 32, HD_ / 32, B_ * NH_), blk, 0, stream>>>(qkv, VT);
  // 5. causal flash attention, paired -> attnb   [256 blocks, 512 thr]
  attn_k<<<dim3(256), dim3(512), 0, stream>>>(qkv, VT, attnb);
  // 6. transpose wo -> W (wqkvT dead after step 3)
  transpose_k<<<dim3(H_ / 32, H_ / 32), blk, 0, stream>>>(wo, W, H_, H_, flagp);
  // 7. out-proj, split-K=2 -> fp32 partials in F (qkv/VT dead)   [256 blocks]
  gemm256<3><<<dim3(2 * (H_ / 256) * (B_ * S_ / 256)), gblk, 0, stream>>>(
      attnb, W, (void*)Pop, nullptr, B_ * S_, H_, H_, flagp, 0, 0, H_ / 256,
      (H_ / 256) * (B_ * S_ / 256), H_ / 2, (size_t)B_ * S_ * H_, H_);
  // 7b. fused reduce + residual(x) + LN2: hbuf = P0+P1+x, hn = LN(hbuf)
  red_ln_k<<<dim3(B_ * S_), blk, 0, stream>>>(
      Pop, hbuf, hn, x, g2, b2, H_, (size_t)B_ * S_ * H_, flagp);
  // 8. transpose w_in -> W (woT dead)
  transpose_k<<<dim3(FF_ / 32, H_ / 32), blk, 0, stream>>>(w_in, W, H_, FF_, flagp);
  // 9. FFN up + GELU: -> ff1 (F; Pop dead)   [512 blocks]
  gemm256<2><<<dim3((FF_ / 256) * (B_ * S_ / 256)), gblk, 0, stream>>>(
      hn, W, ff1, nullptr, B_ * S_, FF_, H_, flagp, 0, 0, FF_ / 256,
      0, H_, 0, 0);
  // 10. transpose w_out -> W (winT dead)
  transpose_k<<<dim3(H_ / 32, FF_ / 32), blk, 0, stream>>>(w_out, W, FF_, H_, flagp);
  // 11. FFN down, split-K=2 -> fp32 partials overlaid in-place on ff1
  //     [256 blocks]  P_ks[r][c] = ((float*)ff1)[ks*2048 + r*4096 + c]
  gemm256<3><<<dim3(2 * (H_ / 256) * (B_ * S_ / 256)), gblk, 0, stream>>>(
      ff1, W, (void*)ff1, nullptr, B_ * S_, H_, FF_, flagp, 0, 0, H_ / 256,
      (H_ / 256) * (B_ * S_ / 256), FF_ / 2, (size_t)H_, 2 * H_);
  // 11b. reduce + residual(hbuf) -> d_out (flag dtype store)
  red_k<<<dim3((B_ * S_ * H_) / (256 * 8)), blk, 0, stream>>>(
      (const float*)ff1, d_out, hbuf, 2 * H_, (size_t)H_, flagp, 0, 1);
}